// Round 20
// baseline (742.237 us; speedup 1.0000x reference)
//
#include <hip/hip_runtime.h>
#include <hip/hip_bf16.h>

#define CC 64
#define HIDN 128
#define DCC 16
#define HH 128
#define WW 128
#define HWS (HH*WW)        // 16384
#define BB 16
#define NPIX (BB*HWS)      // 262144

typedef __hip_bfloat16 bf16;
typedef __attribute__((ext_vector_type(8))) unsigned short ushort8;
typedef __attribute__((ext_vector_type(4))) unsigned short ushort4v;
typedef __attribute__((ext_vector_type(4))) float float4v;
typedef __attribute__((ext_vector_type(8))) short bf16x8;
typedef __attribute__((ext_vector_type(4))) float f32x4;

__device__ __forceinline__ float rcp_fast(float x){ return __builtin_amdgcn_rcpf(x); }
__device__ __forceinline__ float ftanh(float x){
    float e = __expf(2.f*x);
    return 1.f - 2.f*rcp_fast(e + 1.f);
}
__device__ __forceinline__ float fsig(float x){
    return rcp_fast(1.f + __expf(-x));
}
__device__ __forceinline__ float fgelu(float x){
    return x * fsig(x*(1.5957691216f + 0.07135481283f*x*x));
}
__device__ __forceinline__ float b2f(bf16 v){ return __bfloat162float(v); }
__device__ __forceinline__ float u2f(unsigned short u){
    unsigned v = ((unsigned)u) << 16; return __uint_as_float(v);
}
__device__ __forceinline__ unsigned short f2u(float f){
    bf16 h = __float2bfloat16(f);
    return *reinterpret_cast<unsigned short*>(&h);
}
__device__ __forceinline__ bf16x8 packf(float4v a, float4v b){
    bf16x8 r;
    r[0]=(short)f2u(a.x); r[1]=(short)f2u(a.y); r[2]=(short)f2u(a.z); r[3]=(short)f2u(a.w);
    r[4]=(short)f2u(b.x); r[5]=(short)f2u(b.y); r[6]=(short)f2u(b.z); r[7]=(short)f2u(b.w);
    return r;
}

// ---------------------------------------------------------------- gate (R16 version: 512-px blocks, MFMA, zero-shuffle chain)
template<int F32>
__global__ __launch_bounds__(256,2) void k_gate(
    const float* __restrict__ xf, const bf16* __restrict__ xb,
    const float* __restrict__ wz1, const float* __restrict__ bz1,
    const float* __restrict__ wz2, const float* __restrict__ bz2,
    const float* __restrict__ wf1, const float* __restrict__ bf1,
    const float* __restrict__ wf2, const float* __restrict__ bf2,
    bf16* __restrict__ vout)
{
    __shared__ __align__(16) unsigned short xs[512*64];   // 64 KB
    const int t = threadIdx.x;
    const int lane = t & 63;
    const int wv = t >> 6;
    const int col = lane & 15;
    const int g = lane >> 4;
    const int blk = blockIdx.x;
    const int b = blk >> 5;
    const int sp0 = (blk & 31) << 9;

    {
        const int ch = t & 63;
        const int wg = t >> 6;
        const size_t base = ((size_t)b*CC + ch)*HWS + sp0;
        #pragma unroll
        for (int i=0;i<16;++i){
            int bufpx = (wg*16 + i) << 3;
            ushort8 val;
            if (F32){
                float4v a = *reinterpret_cast<const float4v*>(xf + base + bufpx);
                float4v c = *reinterpret_cast<const float4v*>(xf + base + bufpx + 4);
                val[0]=f2u(a.x); val[1]=f2u(a.y); val[2]=f2u(a.z); val[3]=f2u(a.w);
                val[4]=f2u(c.x); val[5]=f2u(c.y); val[6]=f2u(c.z); val[7]=f2u(c.w);
            } else {
                val = *reinterpret_cast<const ushort8*>(xb + base + bufpx);
            }
            #pragma unroll
            for (int j=0;j<8;++j){
                int px = bufpx + j;
                *(unsigned short*)((char*)xs + px*128 + ((ch*2) ^ ((px&7)<<4))) = val[j];
            }
        }
    }

    bf16x8 Az1[4][2], Af1[4][2], Az2[4][2], Af2[4][2];
    #pragma unroll
    for (int ot=0; ot<4; ++ot){
        #pragma unroll
        for (int kh=0; kh<2; ++kh){
            const float* p;
            p = wz1 + (ot*16+col)*64 + kh*32 + g*8;
            Az1[ot][kh] = packf(*(const float4v*)p, *(const float4v*)(p+4));
            p = wf1 + (ot*16+col)*64 + kh*32 + g*8;
            Af1[ot][kh] = packf(*(const float4v*)p, *(const float4v*)(p+4));
            p = wz2 + (ot*16+col)*64 + kh*32 + g*4;
            Az2[ot][kh] = packf(*(const float4v*)p, *(const float4v*)(p+16));
            p = wf2 + (ot*16+col)*64 + kh*32 + g*4;
            Af2[ot][kh] = packf(*(const float4v*)p, *(const float4v*)(p+16));
        }
    }
    __syncthreads();

    bf16* vb = vout + (size_t)b*CC*HWS;

    for (int it = wv; it < 32; it += 4){
        const int lpx = it*16 + col;
        const int px = sp0 + lpx;
        bf16x8 Bx[2];
        Bx[0] = *(const bf16x8*)((char*)xs + lpx*128 + ((g*16) ^ ((lpx&7)<<4)));
        Bx[1] = *(const bf16x8*)((char*)xs + lpx*128 + ((64 + g*16) ^ ((lpx&7)<<4)));
        f32x4 Dz[4], Df[4];
        #pragma unroll
        for (int ot=0; ot<4; ++ot){
            Dz[ot] = *(const f32x4*)(bz1 + ot*16 + g*4);
            Df[ot] = *(const f32x4*)(bf1 + ot*16 + g*4);
        }
        #pragma unroll
        for (int kh=0; kh<2; ++kh)
            #pragma unroll
            for (int ot=0; ot<4; ++ot){
                Dz[ot] = __builtin_amdgcn_mfma_f32_16x16x32_bf16(Az1[ot][kh], Bx[kh], Dz[ot], 0,0,0);
                Df[ot] = __builtin_amdgcn_mfma_f32_16x16x32_bf16(Af1[ot][kh], Bx[kh], Df[ot], 0,0,0);
            }
        #pragma unroll
        for (int ot=0; ot<4; ++ot)
            #pragma unroll
            for (int r=0; r<4; ++r){
                Dz[ot][r] = ftanh(Dz[ot][r]);
                Df[ot][r] = ftanh(Df[ot][r]);
            }
        bf16x8 Bz[2], Bf[2];
        #pragma unroll
        for (int kh=0; kh<2; ++kh)
            #pragma unroll
            for (int j=0; j<4; ++j){
                Bz[kh][j]   = (short)f2u(Dz[2*kh][j]);
                Bz[kh][4+j] = (short)f2u(Dz[2*kh+1][j]);
                Bf[kh][j]   = (short)f2u(Df[2*kh][j]);
                Bf[kh][4+j] = (short)f2u(Df[2*kh+1][j]);
            }
        f32x4 Ez[4], Ef[4];
        #pragma unroll
        for (int ot=0; ot<4; ++ot){
            Ez[ot] = *(const f32x4*)(bz2 + ot*16 + g*4);
            Ef[ot] = *(const f32x4*)(bf2 + ot*16 + g*4);
        }
        #pragma unroll
        for (int kh=0; kh<2; ++kh)
            #pragma unroll
            for (int ot=0; ot<4; ++ot){
                Ez[ot] = __builtin_amdgcn_mfma_f32_16x16x32_bf16(Az2[ot][kh], Bz[kh], Ez[ot], 0,0,0);
                Ef[ot] = __builtin_amdgcn_mfma_f32_16x16x32_bf16(Af2[ot][kh], Bf[kh], Ef[ot], 0,0,0);
            }
        #pragma unroll
        for (int ot=0; ot<4; ++ot)
            #pragma unroll
            for (int r=0; r<4; ++r){
                float Zv = ftanh(Ez[ot][r]);
                float Fv = fsig(Ef[ot][r]);
                *reinterpret_cast<unsigned short*>(vb + (size_t)(ot*16+g*4+r)*HWS + px)
                    = f2u((1.f - Fv)*Zv);
            }
    }
}

// ---------------------------------------------------------------- pl1: pconv(16->16,3x3) FUSED with lin1h (R16 version)
__global__ __launch_bounds__(256) void k_pl1(
    const bf16* __restrict__ v, const float* __restrict__ pw,
    const float* __restrict__ l1w, const float* __restrict__ l1b,
    bf16* __restrict__ x1out, bf16* __restrict__ h1out)
{
    __shared__ __align__(16) unsigned short xs[256*64];   // 32 KB
    __shared__ __align__(16) unsigned short vh[16][4][128]; // 16 KB
    __shared__ __align__(16) unsigned short tr[4][32*66]; // 16.5 KB, wave-private
    const int t = threadIdx.x;
    const int lane = t & 63;
    const int wv = t >> 6;
    const int col = lane & 15;
    const int g = lane >> 4;
    const int blk = blockIdx.x;         // 1024 blocks
    const int b = blk >> 6;
    const int y0 = (blk & 63) << 1;     // 2 rows
    const int sp0 = y0 * WW;

    {
        const int ch = t & 63;
        const int wg = t >> 6;
        if (ch < DCC){
            int gy = y0 - 1 + wg;
            unsigned short* dst = &vh[ch][wg][0];
            if (gy >= 0 && gy < HH){
                const bf16* src = v + ((size_t)b*CC + ch)*HWS + (size_t)gy*WW;
                #pragma unroll
                for (int i=0;i<16;++i)
                    *reinterpret_cast<ushort8*>(dst + i*8) =
                        *reinterpret_cast<const ushort8*>(src + i*8);
            } else {
                #pragma unroll
                for (int i=0;i<16;++i){
                    ushort8 z;
                    #pragma unroll
                    for (int j=0;j<8;++j) z[j]=0;
                    *reinterpret_cast<ushort8*>(dst + i*8) = z;
                }
            }
        } else {
            const bf16* src = v + ((size_t)b*CC + ch)*HWS + sp0;
            #pragma unroll
            for (int i=0;i<8;++i){
                int bufpx = wg*64 + i*8;
                ushort8 val = *reinterpret_cast<const ushort8*>(src + bufpx);
                #pragma unroll
                for (int j=0;j<8;++j){
                    int px = bufpx + j;
                    *(unsigned short*)((char*)xs + px*128 + ((ch*2) ^ ((px&7)<<4))) = val[j];
                }
            }
        }
    }
    __syncthreads();

    {
        const int oc = t >> 4;
        const int px0 = (t & 15) << 3;
        float acc[2][8];
        #pragma unroll
        for (int r=0;r<2;++r)
            #pragma unroll
            for (int i=0;i<8;++i) acc[r][i]=0.f;
        #pragma unroll 1
        for (int ic=0; ic<DCC; ++ic){
            float m[4][10];
            #pragma unroll
            for (int row=0;row<4;++row){
                const unsigned short* rp = &vh[ic][row][px0];
                ushort8 mv = *reinterpret_cast<const ushort8*>(rp);
                #pragma unroll
                for (int i=0;i<8;++i) m[row][i+1] = u2f(mv[i]);
                m[row][0] = (px0>0)    ? u2f(rp[-1]) : 0.f;
                m[row][9] = (px0+8<WW) ? u2f(rp[8])  : 0.f;
            }
            const float* wp = pw + (size_t)(oc*DCC+ic)*9;
            #pragma unroll
            for (int ky=0;ky<3;++ky){
                float w0 = wp[ky*3+0], w1 = wp[ky*3+1], w2 = wp[ky*3+2];
                #pragma unroll
                for (int r=0;r<2;++r)
                    #pragma unroll
                    for (int i=0;i<8;++i)
                        acc[r][i] = fmaf(w0, m[r+ky][i],
                                    fmaf(w1, m[r+ky][i+1],
                                    fmaf(w2, m[r+ky][i+2], acc[r][i])));
            }
        }
        #pragma unroll
        for (int r=0;r<2;++r){
            ushort8 ov;
            #pragma unroll
            for (int i=0;i<8;++i){
                unsigned short uu = f2u(acc[r][i]);
                ov[i] = uu;
                int px = r*128 + px0 + i;
                *(unsigned short*)((char*)xs + px*128 + ((oc*2) ^ ((px&7)<<4))) = uu;
            }
            *reinterpret_cast<ushort8*>(x1out + ((size_t)b*DCC + oc)*HWS
                                        + (size_t)(y0+r)*WW + px0) = ov;
        }
    }
    __syncthreads();

    unsigned short* trw = &tr[wv][0];
    const int lpx0 = wv*64;

    #pragma unroll 1
    for (int oc=0; oc<4; ++oc){
        bf16x8 A1[2][2];
        #pragma unroll
        for (int t2=0;t2<2;++t2)
            #pragma unroll
            for (int kh=0;kh<2;++kh){
                bf16x8 fa;
                #pragma unroll
                for (int j=0;j<8;++j){
                    int cin = kh*32 + g*8 + j;
                    fa[j] = (short)f2u(l1w[cin*256 + oc*32 + t2*16 + col]);
                }
                A1[t2][kh]=fa;
            }
        #pragma unroll
        for (int lt=0;lt<4;++lt){
            int px = lpx0 + lt*16 + col;
            bf16x8 B0 = *(const bf16x8*)((char*)xs + px*128 + ((g*16) ^ ((px&7)<<4)));
            bf16x8 B1 = *(const bf16x8*)((char*)xs + px*128 + ((64 + g*16) ^ ((px&7)<<4)));
            f32x4 D0 = *(const f32x4*)(l1b + oc*32 + g*4);
            f32x4 D1 = *(const f32x4*)(l1b + oc*32 + 16 + g*4);
            D0 = __builtin_amdgcn_mfma_f32_16x16x32_bf16(A1[0][0], B0, D0, 0,0,0);
            D0 = __builtin_amdgcn_mfma_f32_16x16x32_bf16(A1[0][1], B1, D0, 0,0,0);
            D1 = __builtin_amdgcn_mfma_f32_16x16x32_bf16(A1[1][0], B0, D1, 0,0,0);
            D1 = __builtin_amdgcn_mfma_f32_16x16x32_bf16(A1[1][1], B1, D1, 0,0,0);
            int lp = lt*16 + col;
            #pragma unroll
            for (int rr=0;rr<4;++rr){
                trw[(g*4+rr)*66 + lp]    = f2u(fgelu(D0[rr]));
                trw[(16+g*4+rr)*66 + lp] = f2u(fgelu(D1[rr]));
            }
        }
        {
            int ch2 = lane >> 1;
            int half = lane & 1;
            const unsigned short* srcp = trw + ch2*66 + half*32;
            bf16* dst = h1out + ((size_t)(b*HIDN + oc*32 + ch2))*HWS + sp0 + lpx0 + half*32;
            #pragma unroll
            for (int i=0;i<4;++i){
                ushort8 u8 = *reinterpret_cast<const ushort8*>(srcp + i*8);
                *reinterpret_cast<ushort8*>(dst + i*8) = u8;
            }
        }
    }
}

// ---------------------------------------------------------------- wprep: per-layer weight fragments, packed per-lane
__global__ __launch_bounds__(256) void k_wprep(
    const float* __restrict__ l1w_all, const float* __restrict__ w2_all,
    bf16* __restrict__ frag_all)
{
    const int l = blockIdx.x;
    const float* l1w = l1w_all + (size_t)l*CC*256;
    const float* w2  = w2_all  + (size_t)l*HIDN*CC;
    unsigned short* buf1 = (unsigned short*)(frag_all + (size_t)l*16384);
    unsigned short* buf2 = buf1 + 8192;
    const int t = threadIdx.x;
    const int lane = t & 63;
    const int col = lane & 15;
    const int g = lane >> 4;
    #pragma unroll
    for (int c4=0;c4<4;++c4){
        int combo = (t>>6)*4 + c4;          // 0..15
        {
            int cc = combo >> 2, t2 = (combo>>1)&1, kh = combo&1;
            #pragma unroll
            for (int j=0;j<8;++j){
                int cin = kh*32 + g*8 + j;
                buf1[(combo*64 + lane)*8 + j] =
                    f2u(l1w[cin*256 + 128 + cc*32 + t2*16 + col]);
            }
        }
        {
            int cc = combo >> 2, ot = combo & 3;
            #pragma unroll
            for (int j=0;j<8;++j){
                int k = cc*32 + ((j>>2)<<4) + (g<<2) + (j&3);
                buf2[(combo*64 + lane)*8 + j] = f2u(w2[k*64 + ot*16 + col]);
            }
        }
    }
}

// ---------------------------------------------------------------- dwA: dwconv(h1)+gelu + lazy-h2 + gate + lin2 fused
// R20: 2 rows/block at 512 THREADS — halves per-thread state vs R19 (Dx back to
// [2][4]=32 VGPR, 3-row prefetch) so no spill (R19 post-mortem: VGPR pinned 128,
// spill traffic ate the amortization), while keeping 2x amortization of
// x-stage/epilogue/barriers and the 4-vs-6 halo-row win.
__global__ __launch_bounds__(512) void k_dwA(
    const bf16* __restrict__ x1, const bf16* __restrict__ v,
    const bf16* __restrict__ h1, const bf16* __restrict__ wfrag,
    const float* __restrict__ l1b,
    const float* __restrict__ dww, const float* __restrict__ dwb,
    const float* __restrict__ l2b,
    bf16* __restrict__ xout,
    const float* __restrict__ xinit,   // non-null on last layer
    bf16* __restrict__ xsum)
{
    __shared__ __align__(16) unsigned short xs[256*64];    // 32 KB (2 rows)
    __shared__ __align__(16) unsigned short ub[16896];     // 33.8 KB: chunks [row][32cj][260]; epilogue [64ch][264]
    const int t = threadIdx.x;
    const int lane = t & 63;
    const int wv = t >> 6;          // 0..7
    const int col = lane & 15;
    const int g = lane >> 4;
    const int blk0 = blockIdx.x;          // 1024 blocks
    const int blk = (blk0 & 7)*128 + (blk0 >> 3);   // XCD-contiguous
    const int b = blk >> 6;
    const int y0 = (blk & 63) << 1;       // 2 rows y0, y0+1

    const int grp = t & 15;          // dw: row/px group
    const int drow = grp >> 3;       // 0..1
    const int pxo  = (grp & 7) << 4; // 16-px group
    const int cj   = t >> 4;         // 0..31 dw channel within chunk

    const unsigned short* buf1 = (const unsigned short*)wfrag;
    const unsigned short* buf2 = buf1 + 8192;

    // ---- prefetch state: 3 h1 rows for THIS thread's output row, chunk-ahead
    ushort8 pfa[3], pfb[3];
    unsigned short pfl[3], pfr[3];
    float pw9[9], pbj;
    auto LOADCHUNK = [&](int cc){
        int chg = cc*32 + cj;
        const bf16* h1p = h1 + ((size_t)(b*HIDN + chg))*HWS;
        #pragma unroll
        for (int ky=0; ky<3; ++ky){
            int gy = y0 + drow + ky - 1;
            if (gy >= 0 && gy < HH){
                const bf16* rp = h1p + (size_t)gy*WW + pxo;
                pfa[ky] = *reinterpret_cast<const ushort8*>(rp);
                pfb[ky] = *reinterpret_cast<const ushort8*>(rp+8);
                pfl[ky] = (pxo>0)     ? *reinterpret_cast<const unsigned short*>(rp-1)  : 0;
                pfr[ky] = (pxo+16<WW) ? *reinterpret_cast<const unsigned short*>(rp+16) : 0;
            } else {
                #pragma unroll
                for (int i=0;i<8;++i){ pfa[ky][i]=0; pfb[ky][i]=0; }
                pfl[ky]=0; pfr[ky]=0;
            }
        }
        #pragma unroll
        for (int i=0;i<9;++i) pw9[i] = dww[chg*9+i];
        pbj = dwb[chg];
    };

    LOADCHUNK(0);

    {   // stage x-cat 2 rows: 64ch x 256px (rows contiguous in global)
        const int ch = t & 63;
        const int wg = t >> 6;           // 0..7
        const bf16* src = (ch < DCC) ? x1 + ((size_t)b*DCC + ch)*HWS
                                     : v  + ((size_t)b*CC  + ch)*HWS;
        const size_t base = (size_t)y0*WW;
        #pragma unroll
        for (int i=0;i<4;++i){
            int bufpx = wg*32 + i*8;
            ushort8 val = *reinterpret_cast<const ushort8*>(src + base + bufpx);
            #pragma unroll
            for (int j=0;j<8;++j){
                int px = bufpx + j;
                *(unsigned short*)((char*)xs + px*128 + ((ch*2) ^ ((px&7)<<4))) = val[j];
            }
        }
    }
    __syncthreads();

    f32x4 Dx[2][4];
    #pragma unroll
    for (int q=0;q<2;++q)
        #pragma unroll
        for (int ot=0;ot<4;++ot)
            Dx[q][ot] = *(const f32x4*)(l2b + ot*16 + g*4);

    #pragma unroll 1
    for (int cc=0; cc<4; ++cc){
        // ---- dw conv for this thread's row from prefetched regs -> u
        ushort8 o0v, o1v;
        {
            float acc[16];
            #pragma unroll
            for (int i=0;i<16;++i) acc[i]=0.f;
            #pragma unroll
            for (int ky=0; ky<3; ++ky){
                float m[16];
                #pragma unroll
                for (int i=0;i<8;++i){ m[i]=u2f(pfa[ky][i]); m[8+i]=u2f(pfb[ky][i]); }
                float lf = u2f(pfl[ky]);
                float rt = u2f(pfr[ky]);
                float w0=pw9[ky*3], w1=pw9[ky*3+1], wv2=pw9[ky*3+2];
                #pragma unroll
                for (int i=0;i<16;++i){
                    float l  = i ? m[i-1] : lf;
                    float r_ = (i==15) ? rt : m[i+1];
                    acc[i] = fmaf(w0,l, fmaf(w1,m[i], fmaf(wv2,r_,acc[i])));
                }
            }
            #pragma unroll
            for (int i=0;i<8;++i){
                o0v[i] = f2u(fgelu(acc[i]+pbj));
                o1v[i] = f2u(fgelu(acc[8+i]+pbj));
            }
        }
        if (cc < 3) LOADCHUNK(cc+1);
        *(ushort8*)(ub + drow*8320 + cj*260 + pxo)     = o0v;
        *(ushort8*)(ub + drow*8320 + cj*260 + pxo + 8) = o1v;
        __syncthreads();
        // ---- fused: lazy h2 MFMA + gate (in-reg) + lin2 MFMA; frags from L2
        {
            bf16x8 A1g[2][2];
            #pragma unroll
            for (int t2=0;t2<2;++t2)
                #pragma unroll
                for (int kh=0;kh<2;++kh){
                    int combo = (cc*2+t2)*2+kh;
                    ushort8 u = *reinterpret_cast<const ushort8*>(buf1 + (combo*64 + lane)*8);
                    bf16x8 f;
                    #pragma unroll
                    for (int j=0;j<8;++j) f[j]=(short)u[j];
                    A1g[t2][kh]=f;
                }
            bf16x8 A2[4];
            #pragma unroll
            for (int ot=0;ot<4;++ot){
                int combo = cc*4+ot;
                ushort8 u = *reinterpret_cast<const ushort8*>(buf2 + (combo*64 + lane)*8);
                bf16x8 f;
                #pragma unroll
                for (int j=0;j<8;++j) f[j]=(short)u[j];
                A2[ot] = f;
            }
            #pragma unroll
            for (int q=0;q<2;++q){
                int pxs = (wv*2+q)*16 + col;          // 0..255 staged px
                int row = pxs >> 7, px = pxs & 127;
                bf16x8 B0 = *(const bf16x8*)((char*)xs + pxs*128 + ((g*16) ^ ((pxs&7)<<4)));
                bf16x8 B1 = *(const bf16x8*)((char*)xs + pxs*128 + ((64 + g*16) ^ ((pxs&7)<<4)));
                f32x4 D0 = *(const f32x4*)(l1b + 128 + cc*32 + g*4);
                f32x4 D1 = *(const f32x4*)(l1b + 128 + cc*32 + 16 + g*4);
                D0 = __builtin_amdgcn_mfma_f32_16x16x32_bf16(A1g[0][0], B0, D0, 0,0,0);
                D0 = __builtin_amdgcn_mfma_f32_16x16x32_bf16(A1g[0][1], B1, D0, 0,0,0);
                D1 = __builtin_amdgcn_mfma_f32_16x16x32_bf16(A1g[1][0], B0, D1, 0,0,0);
                D1 = __builtin_amdgcn_mfma_f32_16x16x32_bf16(A1g[1][1], B1, D1, 0,0,0);
                bf16x8 Bg;
                #pragma unroll
                for (int j=0;j<4;++j){
                    float u0 = u2f(ub[row*8320 + (g*4+j)*260 + px]);
                    float u1 = u2f(ub[row*8320 + (16+g*4+j)*260 + px]);
                    Bg[j]   = (short)f2u(u0 * fgelu(D0[j]));
                    Bg[4+j] = (short)f2u(u1 * fgelu(D1[j]));
                }
                #pragma unroll
                for (int ot=0;ot<4;++ot)
                    Dx[q][ot] = __builtin_amdgcn_mfma_f32_16x16x32_bf16(A2[ot], Bg, Dx[q][ot], 0,0,0);
            }
        }
        __syncthreads();    // before next chunk's dw overwrites ub
    }
    // ---- epilogue: transpose Dx through ub [ch][264], then coalesced writes (2 rows)
    #pragma unroll
    for (int q=0;q<2;++q)
        #pragma unroll
        for (int ot=0;ot<4;++ot)
            #pragma unroll
            for (int rr=0;rr<4;++rr)
                ub[(ot*16 + g*4 + rr)*264 + (wv*2+q)*16 + col] = f2u(Dx[q][ot][rr]);
    __syncthreads();
    {
        int ch   = t >> 3;               // 0..63
        int part = t & 7;                // 8 x 32-px blocks
        int pxb  = part*32;
        size_t off = ((size_t)(b*CC + ch))*HWS + (size_t)y0*WW + pxb;
        #pragma unroll
        for (int i=0;i<4;++i){
            ushort8 dv = *reinterpret_cast<const ushort8*>(ub + ch*264 + pxb + i*8);
            ushort8 vv = *reinterpret_cast<const ushort8*>(v + off + i*8);
            ushort8 ov;
            float rv[8];
            #pragma unroll
            for (int j=0;j<8;++j){
                rv[j] = u2f(dv[j]) + u2f(vv[j]);
                ov[j] = f2u(rv[j]);
            }
            *reinterpret_cast<ushort8*>(xout + off + i*8) = ov;
            if (xinit){
                float4v x0 = *reinterpret_cast<const float4v*>(xinit + off + i*8);
                float4v x1v = *reinterpret_cast<const float4v*>(xinit + off + i*8 + 4);
                ushort8 sv;
                sv[0]=f2u(rv[0]+x0.x); sv[1]=f2u(rv[1]+x0.y);
                sv[2]=f2u(rv[2]+x0.z); sv[3]=f2u(rv[3]+x0.w);
                sv[4]=f2u(rv[4]+x1v.x); sv[5]=f2u(rv[5]+x1v.y);
                sv[6]=f2u(rv[6]+x1v.z); sv[7]=f2u(rv[7]+x1v.w);
                *reinterpret_cast<ushort8*>(xsum + off + i*8) = sv;
            }
        }
    }
}

// ---------------------------------------------------------------- final conv (64->1, 3x3), 8 px/thread
__global__ __launch_bounds__(256) void k_final(
    const bf16* __restrict__ s, const float* __restrict__ w,
    const float* __restrict__ bias, float* __restrict__ out)
{
    int gid = blockIdx.x*256 + threadIdx.x;   // thread = 8 px
    int b = gid >> 11;
    int sp8 = (gid & 2047) << 3;
    int y = sp8 >> 7, x0 = sp8 & 127;
    const bf16* sb = s + (size_t)b*CC*HWS;
    float acc[8];
    #pragma unroll
    for (int i=0;i<8;++i) acc[i] = bias[0];

    #pragma unroll 1
    for (int c=0;c<CC;++c){
        const bf16* ip = sb + (size_t)c*HWS;
        const float* wp = w + (size_t)c*9;
        #pragma unroll
        for (int ky=0;ky<3;++ky){
            int yy = y + ky - 1;
            float xv[10];
            if (yy >= 0 && yy < HH){
                const bf16* rp = ip + yy*WW + x0;
                ushort8 mv = *reinterpret_cast<const ushort8*>(rp);
                #pragma unroll
                for (int i=0;i<8;++i) xv[i+1]=u2f(mv[i]);
                xv[0] = (x0>0)    ? b2f(rp[-1]) : 0.f;
                xv[9] = (x0+8<WW) ? b2f(rp[8])  : 0.f;
            } else {
                #pragma unroll
                for (int i=0;i<10;++i) xv[i] = 0.f;
            }
            float w0 = wp[ky*3+0], w1 = wp[ky*3+1], w2 = wp[ky*3+2];
            #pragma unroll
            for (int i=0;i<8;++i)
                acc[i] = fmaf(w0, xv[i],
                         fmaf(w1, xv[i+1],
                         fmaf(w2, xv[i+2], acc[i])));
        }
    }
    float4v o0, o1;
    o0.x=acc[0]; o0.y=acc[1]; o0.z=acc[2]; o0.w=acc[3];
    o1.x=acc[4]; o1.y=acc[5]; o1.z=acc[6]; o1.w=acc[7];
    float* op = out + (size_t)gid*8;
    *reinterpret_cast<float4v*>(op)     = o0;
    *reinterpret_cast<float4v*>(op + 4) = o1;
}

// ---------------------------------------------------------------- launch
extern "C" void kernel_launch(void* const* d_in, const int* in_sizes, int n_in,
                              void* d_out, int out_size, void* d_ws, size_t ws_size,
                              hipStream_t stream)
{
    const float* x    = (const float*)d_in[0];
    const float* wz1  = (const float*)d_in[1];
    const float* bz1  = (const float*)d_in[2];
    const float* wz2  = (const float*)d_in[3];
    const float* bz2  = (const float*)d_in[4];
    const float* wf1  = (const float*)d_in[5];
    const float* bf1  = (const float*)d_in[6];
    const float* wf2  = (const float*)d_in[7];
    const float* bf2  = (const float*)d_in[8];
    const float* pw   = (const float*)d_in[9];
    const float* l1w  = (const float*)d_in[10];
    const float* l1b  = (const float*)d_in[11];
    const float* dww  = (const float*)d_in[12];
    const float* dwb  = (const float*)d_in[13];
    const float* l2w  = (const float*)d_in[14];
    const float* l2b  = (const float*)d_in[15];
    const float* ow   = (const float*)d_in[16];
    const float* obb  = (const float*)d_in[17];

    char* ws = (char*)d_ws;
    bf16* xc    = (bf16*)(ws);                    // 33,554,432 B
    bf16* v     = (bf16*)(ws + 33554432);         // 33,554,432 B
    bf16* x1    = (bf16*)(ws + 67108864);         //  8,388,608 B
    bf16* xsumb = (bf16*)(ws + 75497472);         // 33,554,432 B
    bf16* h1buf = (bf16*)(ws + 109051904);        // 67,108,864 B
    bf16* wfrag = (bf16*)(ws + 176160768);        // 3 x 32 KB

    k_wprep<<<3, 256, 0, stream>>>(l1w, l2w, wfrag);
    for (int l=0;l<3;++l){
        if (l == 0)
            k_gate<1><<<512, 256, 0, stream>>>(x, nullptr,
                wz1 + l*CC*CC, bz1 + l*CC, wz2 + l*CC*CC, bz2 + l*CC,
                wf1 + l*CC*CC, bf1 + l*CC, wf2 + l*CC*CC, bf2 + l*CC, v);
        else
            k_gate<0><<<512, 256, 0, stream>>>(nullptr, xc,
                wz1 + l*CC*CC, bz1 + l*CC, wz2 + l*CC*CC, bz2 + l*CC,
                wf1 + l*CC*CC, bf1 + l*CC, wf2 + l*CC*CC, bf2 + l*CC, v);
        k_pl1  <<<NPIX/256, 256, 0, stream>>>(v, pw + l*DCC*DCC*9,
                l1w + l*CC*256, l1b + l*256, x1, h1buf);
        k_dwA  <<<BB*HH/2, 512, 0, stream>>>(x1, v, h1buf, wfrag + (size_t)l*16384,
                l1b + l*256,
                dww + l*HIDN*9, dwb + l*HIDN,
                l2b + l*CC,
                xc, (l==2) ? x : nullptr, xsumb);
    }
    k_final<<<NPIX/(256*8), 256, 0, stream>>>(xsumb, ow, obb, (float*)d_out);
}

// Round 21
// 664.246 us; speedup vs baseline: 1.1174x; 1.1174x over previous
//
#include <hip/hip_runtime.h>
#include <hip/hip_bf16.h>

#define CC 64
#define HIDN 128
#define DCC 16
#define HH 128
#define WW 128
#define HWS (HH*WW)        // 16384
#define BB 16
#define NPIX (BB*HWS)      // 262144

typedef __hip_bfloat16 bf16;
typedef __attribute__((ext_vector_type(8))) unsigned short ushort8;
typedef __attribute__((ext_vector_type(4))) unsigned short ushort4v;
typedef __attribute__((ext_vector_type(4))) float float4v;
typedef __attribute__((ext_vector_type(8))) short bf16x8;
typedef __attribute__((ext_vector_type(4))) float f32x4;

__device__ __forceinline__ float rcp_fast(float x){ return __builtin_amdgcn_rcpf(x); }
__device__ __forceinline__ float ftanh(float x){
    float e = __expf(2.f*x);
    return 1.f - 2.f*rcp_fast(e + 1.f);
}
__device__ __forceinline__ float fsig(float x){
    return rcp_fast(1.f + __expf(-x));
}
__device__ __forceinline__ float fgelu(float x){
    return x * fsig(x*(1.5957691216f + 0.07135481283f*x*x));
}
__device__ __forceinline__ float b2f(bf16 v){ return __bfloat162float(v); }
__device__ __forceinline__ float u2f(unsigned short u){
    unsigned v = ((unsigned)u) << 16; return __uint_as_float(v);
}
__device__ __forceinline__ unsigned short f2u(float f){
    bf16 h = __float2bfloat16(f);
    return *reinterpret_cast<unsigned short*>(&h);
}
__device__ __forceinline__ bf16x8 packf(float4v a, float4v b){
    bf16x8 r;
    r[0]=(short)f2u(a.x); r[1]=(short)f2u(a.y); r[2]=(short)f2u(a.z); r[3]=(short)f2u(a.w);
    r[4]=(short)f2u(b.x); r[5]=(short)f2u(b.y); r[6]=(short)f2u(b.z); r[7]=(short)f2u(b.w);
    return r;
}

// ---------------------------------------------------------------- gate (R16: 512-px blocks, MFMA, zero-shuffle chain)
template<int F32>
__global__ __launch_bounds__(256,2) void k_gate(
    const float* __restrict__ xf, const bf16* __restrict__ xb,
    const float* __restrict__ wz1, const float* __restrict__ bz1,
    const float* __restrict__ wz2, const float* __restrict__ bz2,
    const float* __restrict__ wf1, const float* __restrict__ bf1,
    const float* __restrict__ wf2, const float* __restrict__ bf2,
    bf16* __restrict__ vout)
{
    __shared__ __align__(16) unsigned short xs[512*64];   // 64 KB
    const int t = threadIdx.x;
    const int lane = t & 63;
    const int wv = t >> 6;
    const int col = lane & 15;
    const int g = lane >> 4;
    const int blk = blockIdx.x;
    const int b = blk >> 5;
    const int sp0 = (blk & 31) << 9;

    {
        const int ch = t & 63;
        const int wg = t >> 6;
        const size_t base = ((size_t)b*CC + ch)*HWS + sp0;
        #pragma unroll
        for (int i=0;i<16;++i){
            int bufpx = (wg*16 + i) << 3;
            ushort8 val;
            if (F32){
                float4v a = *reinterpret_cast<const float4v*>(xf + base + bufpx);
                float4v c = *reinterpret_cast<const float4v*>(xf + base + bufpx + 4);
                val[0]=f2u(a.x); val[1]=f2u(a.y); val[2]=f2u(a.z); val[3]=f2u(a.w);
                val[4]=f2u(c.x); val[5]=f2u(c.y); val[6]=f2u(c.z); val[7]=f2u(c.w);
            } else {
                val = *reinterpret_cast<const ushort8*>(xb + base + bufpx);
            }
            #pragma unroll
            for (int j=0;j<8;++j){
                int px = bufpx + j;
                *(unsigned short*)((char*)xs + px*128 + ((ch*2) ^ ((px&7)<<4))) = val[j];
            }
        }
    }

    bf16x8 Az1[4][2], Af1[4][2], Az2[4][2], Af2[4][2];
    #pragma unroll
    for (int ot=0; ot<4; ++ot){
        #pragma unroll
        for (int kh=0; kh<2; ++kh){
            const float* p;
            p = wz1 + (ot*16+col)*64 + kh*32 + g*8;
            Az1[ot][kh] = packf(*(const float4v*)p, *(const float4v*)(p+4));
            p = wf1 + (ot*16+col)*64 + kh*32 + g*8;
            Af1[ot][kh] = packf(*(const float4v*)p, *(const float4v*)(p+4));
            p = wz2 + (ot*16+col)*64 + kh*32 + g*4;
            Az2[ot][kh] = packf(*(const float4v*)p, *(const float4v*)(p+16));
            p = wf2 + (ot*16+col)*64 + kh*32 + g*4;
            Af2[ot][kh] = packf(*(const float4v*)p, *(const float4v*)(p+16));
        }
    }
    __syncthreads();

    bf16* vb = vout + (size_t)b*CC*HWS;

    for (int it = wv; it < 32; it += 4){
        const int lpx = it*16 + col;
        const int px = sp0 + lpx;
        bf16x8 Bx[2];
        Bx[0] = *(const bf16x8*)((char*)xs + lpx*128 + ((g*16) ^ ((lpx&7)<<4)));
        Bx[1] = *(const bf16x8*)((char*)xs + lpx*128 + ((64 + g*16) ^ ((lpx&7)<<4)));
        f32x4 Dz[4], Df[4];
        #pragma unroll
        for (int ot=0; ot<4; ++ot){
            Dz[ot] = *(const f32x4*)(bz1 + ot*16 + g*4);
            Df[ot] = *(const f32x4*)(bf1 + ot*16 + g*4);
        }
        #pragma unroll
        for (int kh=0; kh<2; ++kh)
            #pragma unroll
            for (int ot=0; ot<4; ++ot){
                Dz[ot] = __builtin_amdgcn_mfma_f32_16x16x32_bf16(Az1[ot][kh], Bx[kh], Dz[ot], 0,0,0);
                Df[ot] = __builtin_amdgcn_mfma_f32_16x16x32_bf16(Af1[ot][kh], Bx[kh], Df[ot], 0,0,0);
            }
        #pragma unroll
        for (int ot=0; ot<4; ++ot)
            #pragma unroll
            for (int r=0; r<4; ++r){
                Dz[ot][r] = ftanh(Dz[ot][r]);
                Df[ot][r] = ftanh(Df[ot][r]);
            }
        bf16x8 Bz[2], Bf[2];
        #pragma unroll
        for (int kh=0; kh<2; ++kh)
            #pragma unroll
            for (int j=0; j<4; ++j){
                Bz[kh][j]   = (short)f2u(Dz[2*kh][j]);
                Bz[kh][4+j] = (short)f2u(Dz[2*kh+1][j]);
                Bf[kh][j]   = (short)f2u(Df[2*kh][j]);
                Bf[kh][4+j] = (short)f2u(Df[2*kh+1][j]);
            }
        f32x4 Ez[4], Ef[4];
        #pragma unroll
        for (int ot=0; ot<4; ++ot){
            Ez[ot] = *(const f32x4*)(bz2 + ot*16 + g*4);
            Ef[ot] = *(const f32x4*)(bf2 + ot*16 + g*4);
        }
        #pragma unroll
        for (int kh=0; kh<2; ++kh)
            #pragma unroll
            for (int ot=0; ot<4; ++ot){
                Ez[ot] = __builtin_amdgcn_mfma_f32_16x16x32_bf16(Az2[ot][kh], Bz[kh], Ez[ot], 0,0,0);
                Ef[ot] = __builtin_amdgcn_mfma_f32_16x16x32_bf16(Af2[ot][kh], Bf[kh], Ef[ot], 0,0,0);
            }
        #pragma unroll
        for (int ot=0; ot<4; ++ot)
            #pragma unroll
            for (int r=0; r<4; ++r){
                float Zv = ftanh(Ez[ot][r]);
                float Fv = fsig(Ef[ot][r]);
                *reinterpret_cast<unsigned short*>(vb + (size_t)(ot*16+g*4+r)*HWS + px)
                    = f2u((1.f - Fv)*Zv);
            }
    }
}

// ---------------------------------------------------------------- pl1: pconv(16->16,3x3) FUSED with lin1h (R16)
__global__ __launch_bounds__(256) void k_pl1(
    const bf16* __restrict__ v, const float* __restrict__ pw,
    const float* __restrict__ l1w, const float* __restrict__ l1b,
    bf16* __restrict__ x1out, bf16* __restrict__ h1out)
{
    __shared__ __align__(16) unsigned short xs[256*64];   // 32 KB
    __shared__ __align__(16) unsigned short vh[16][4][128]; // 16 KB
    __shared__ __align__(16) unsigned short tr[4][32*66]; // 16.5 KB, wave-private
    const int t = threadIdx.x;
    const int lane = t & 63;
    const int wv = t >> 6;
    const int col = lane & 15;
    const int g = lane >> 4;
    const int blk = blockIdx.x;         // 1024 blocks
    const int b = blk >> 6;
    const int y0 = (blk & 63) << 1;     // 2 rows
    const int sp0 = y0 * WW;

    {
        const int ch = t & 63;
        const int wg = t >> 6;
        if (ch < DCC){
            int gy = y0 - 1 + wg;
            unsigned short* dst = &vh[ch][wg][0];
            if (gy >= 0 && gy < HH){
                const bf16* src = v + ((size_t)b*CC + ch)*HWS + (size_t)gy*WW;
                #pragma unroll
                for (int i=0;i<16;++i)
                    *reinterpret_cast<ushort8*>(dst + i*8) =
                        *reinterpret_cast<const ushort8*>(src + i*8);
            } else {
                #pragma unroll
                for (int i=0;i<16;++i){
                    ushort8 z;
                    #pragma unroll
                    for (int j=0;j<8;++j) z[j]=0;
                    *reinterpret_cast<ushort8*>(dst + i*8) = z;
                }
            }
        } else {
            const bf16* src = v + ((size_t)b*CC + ch)*HWS + sp0;
            #pragma unroll
            for (int i=0;i<8;++i){
                int bufpx = wg*64 + i*8;
                ushort8 val = *reinterpret_cast<const ushort8*>(src + bufpx);
                #pragma unroll
                for (int j=0;j<8;++j){
                    int px = bufpx + j;
                    *(unsigned short*)((char*)xs + px*128 + ((ch*2) ^ ((px&7)<<4))) = val[j];
                }
            }
        }
    }
    __syncthreads();

    {
        const int oc = t >> 4;
        const int px0 = (t & 15) << 3;
        float acc[2][8];
        #pragma unroll
        for (int r=0;r<2;++r)
            #pragma unroll
            for (int i=0;i<8;++i) acc[r][i]=0.f;
        #pragma unroll 1
        for (int ic=0; ic<DCC; ++ic){
            float m[4][10];
            #pragma unroll
            for (int row=0;row<4;++row){
                const unsigned short* rp = &vh[ic][row][px0];
                ushort8 mv = *reinterpret_cast<const ushort8*>(rp);
                #pragma unroll
                for (int i=0;i<8;++i) m[row][i+1] = u2f(mv[i]);
                m[row][0] = (px0>0)    ? u2f(rp[-1]) : 0.f;
                m[row][9] = (px0+8<WW) ? u2f(rp[8])  : 0.f;
            }
            const float* wp = pw + (size_t)(oc*DCC+ic)*9;
            #pragma unroll
            for (int ky=0;ky<3;++ky){
                float w0 = wp[ky*3+0], w1 = wp[ky*3+1], w2 = wp[ky*3+2];
                #pragma unroll
                for (int r=0;r<2;++r)
                    #pragma unroll
                    for (int i=0;i<8;++i)
                        acc[r][i] = fmaf(w0, m[r+ky][i],
                                    fmaf(w1, m[r+ky][i+1],
                                    fmaf(w2, m[r+ky][i+2], acc[r][i])));
            }
        }
        #pragma unroll
        for (int r=0;r<2;++r){
            ushort8 ov;
            #pragma unroll
            for (int i=0;i<8;++i){
                unsigned short uu = f2u(acc[r][i]);
                ov[i] = uu;
                int px = r*128 + px0 + i;
                *(unsigned short*)((char*)xs + px*128 + ((oc*2) ^ ((px&7)<<4))) = uu;
            }
            *reinterpret_cast<ushort8*>(x1out + ((size_t)b*DCC + oc)*HWS
                                        + (size_t)(y0+r)*WW + px0) = ov;
        }
    }
    __syncthreads();

    unsigned short* trw = &tr[wv][0];
    const int lpx0 = wv*64;

    #pragma unroll 1
    for (int oc=0; oc<4; ++oc){
        bf16x8 A1[2][2];
        #pragma unroll
        for (int t2=0;t2<2;++t2)
            #pragma unroll
            for (int kh=0;kh<2;++kh){
                bf16x8 fa;
                #pragma unroll
                for (int j=0;j<8;++j){
                    int cin = kh*32 + g*8 + j;
                    fa[j] = (short)f2u(l1w[cin*256 + oc*32 + t2*16 + col]);
                }
                A1[t2][kh]=fa;
            }
        #pragma unroll
        for (int lt=0;lt<4;++lt){
            int px = lpx0 + lt*16 + col;
            bf16x8 B0 = *(const bf16x8*)((char*)xs + px*128 + ((g*16) ^ ((px&7)<<4)));
            bf16x8 B1 = *(const bf16x8*)((char*)xs + px*128 + ((64 + g*16) ^ ((px&7)<<4)));
            f32x4 D0 = *(const f32x4*)(l1b + oc*32 + g*4);
            f32x4 D1 = *(const f32x4*)(l1b + oc*32 + 16 + g*4);
            D0 = __builtin_amdgcn_mfma_f32_16x16x32_bf16(A1[0][0], B0, D0, 0,0,0);
            D0 = __builtin_amdgcn_mfma_f32_16x16x32_bf16(A1[0][1], B1, D0, 0,0,0);
            D1 = __builtin_amdgcn_mfma_f32_16x16x32_bf16(A1[1][0], B0, D1, 0,0,0);
            D1 = __builtin_amdgcn_mfma_f32_16x16x32_bf16(A1[1][1], B1, D1, 0,0,0);
            int lp = lt*16 + col;
            #pragma unroll
            for (int rr=0;rr<4;++rr){
                trw[(g*4+rr)*66 + lp]    = f2u(fgelu(D0[rr]));
                trw[(16+g*4+rr)*66 + lp] = f2u(fgelu(D1[rr]));
            }
        }
        {
            int ch2 = lane >> 1;
            int half = lane & 1;
            const unsigned short* srcp = trw + ch2*66 + half*32;
            bf16* dst = h1out + ((size_t)(b*HIDN + oc*32 + ch2))*HWS + sp0 + lpx0 + half*32;
            #pragma unroll
            for (int i=0;i<4;++i){
                ushort8 u8 = *reinterpret_cast<const ushort8*>(srcp + i*8);
                *reinterpret_cast<ushort8*>(dst + i*8) = u8;
            }
        }
    }
}

// ---------------------------------------------------------------- wprep: per-layer weight fragments, packed per-lane
__global__ __launch_bounds__(256) void k_wprep(
    const float* __restrict__ l1w_all, const float* __restrict__ w2_all,
    bf16* __restrict__ frag_all)
{
    const int l = blockIdx.x;
    const float* l1w = l1w_all + (size_t)l*CC*256;
    const float* w2  = w2_all  + (size_t)l*HIDN*CC;
    unsigned short* buf1 = (unsigned short*)(frag_all + (size_t)l*16384);
    unsigned short* buf2 = buf1 + 8192;
    const int t = threadIdx.x;
    const int lane = t & 63;
    const int col = lane & 15;
    const int g = lane >> 4;
    #pragma unroll
    for (int c4=0;c4<4;++c4){
        int combo = (t>>6)*4 + c4;          // 0..15
        {
            int cc = combo >> 2, t2 = (combo>>1)&1, kh = combo&1;
            #pragma unroll
            for (int j=0;j<8;++j){
                int cin = kh*32 + g*8 + j;
                buf1[(combo*64 + lane)*8 + j] =
                    f2u(l1w[cin*256 + 128 + cc*32 + t2*16 + col]);
            }
        }
        {
            int cc = combo >> 2, ot = combo & 3;
            #pragma unroll
            for (int j=0;j<8;++j){
                int k = cc*32 + ((j>>2)<<4) + (g<<2) + (j&3);
                buf2[(combo*64 + lane)*8 + j] = f2u(w2[k*64 + ot*16 + col]);
            }
        }
    }
}

// ---------------------------------------------------------------- dwA: dwconv(h1)+gelu + lazy-h2 + gate + lin2 fused (R15/R16 version)
__global__ __launch_bounds__(256) void k_dwA(
    const bf16* __restrict__ x1, const bf16* __restrict__ v,
    const bf16* __restrict__ h1, const bf16* __restrict__ wfrag,
    const float* __restrict__ l1b,
    const float* __restrict__ dww, const float* __restrict__ dwb,
    const float* __restrict__ l2b,
    bf16* __restrict__ xout,
    const float* __restrict__ xinit,   // non-null on last layer
    bf16* __restrict__ xsum)
{
    __shared__ __align__(16) unsigned short xs[128*64];    // 16 KB (center row)
    __shared__ __align__(16) unsigned short ubuf[2*8320];  // 33.3 KB
    const int t = threadIdx.x;
    const int lane = t & 63;
    const int wv = t >> 6;
    const int col = lane & 15;
    const int g = lane >> 4;
    const int blk0 = blockIdx.x;          // 2048 blocks
    const int blk = (blk0 & 7)*256 + (blk0 >> 3);   // XCD-contiguous rows
    const int b = blk >> 7;
    const int y = blk & 127;

    const int cj  = (t>>3) & 31;     // dw channel within chunk
    const int pxo = (t & 7) << 4;    // dw 16-px group

    const unsigned short* buf1 = (const unsigned short*)wfrag;
    const unsigned short* buf2 = buf1 + 8192;

    ushort8 pfa[3], pfb[3];
    unsigned short pfl[3], pfr[3];
    float pw9[9], pbj;
    auto LOADCHUNK = [&](int cc){
        int chg = cc*32 + cj;
        const bf16* h1p = h1 + ((size_t)(b*HIDN + chg))*HWS;
        #pragma unroll
        for (int ky=0; ky<3; ++ky){
            int gy = y + ky - 1;
            if (gy >= 0 && gy < HH){
                const bf16* rp = h1p + (size_t)gy*WW + pxo;
                pfa[ky] = *reinterpret_cast<const ushort8*>(rp);
                pfb[ky] = *reinterpret_cast<const ushort8*>(rp+8);
                pfl[ky] = (pxo>0)     ? *reinterpret_cast<const unsigned short*>(rp-1)  : 0;
                pfr[ky] = (pxo+16<WW) ? *reinterpret_cast<const unsigned short*>(rp+16) : 0;
            } else {
                #pragma unroll
                for (int i=0;i<8;++i){ pfa[ky][i]=0; pfb[ky][i]=0; }
                pfl[ky]=0; pfr[ky]=0;
            }
        }
        #pragma unroll
        for (int i=0;i<9;++i) pw9[i] = dww[chg*9+i];
        pbj = dwb[chg];
    };

    LOADCHUNK(0);

    {   // stage x-cat center row: 64ch x 128px
        const int ch = t & 63;
        const int wg = t >> 6;
        const bf16* src = (ch < DCC) ? x1 + ((size_t)b*DCC + ch)*HWS
                                     : v  + ((size_t)b*CC  + ch)*HWS;
        #pragma unroll
        for (int i=0;i<2;++i){
            int bufpx = (wg*2 + i) << 3;
            ushort8 val = *reinterpret_cast<const ushort8*>(src + (size_t)y*WW + bufpx);
            #pragma unroll
            for (int j=0;j<8;++j){
                int px = bufpx + j;
                *(unsigned short*)((char*)xs + px*128 + ((ch*2) ^ ((px&7)<<4))) = val[j];
            }
        }
    }
    __syncthreads();

    f32x4 Dx[2][4];
    #pragma unroll
    for (int q=0;q<2;++q)
        #pragma unroll
        for (int ot=0;ot<4;++ot)
            Dx[q][ot] = *(const f32x4*)(l2b + ot*16 + g*4);

    #pragma unroll 1
    for (int cc=0; cc<4; ++cc){
        unsigned short* ub = ubuf + (cc&1)*8320;
        ushort8 o0v, o1v;
        {
            float acc[16];
            #pragma unroll
            for (int i=0;i<16;++i) acc[i]=0.f;
            #pragma unroll
            for (int ky=0; ky<3; ++ky){
                float m[16];
                #pragma unroll
                for (int i=0;i<8;++i){ m[i]=u2f(pfa[ky][i]); m[8+i]=u2f(pfb[ky][i]); }
                float lf = u2f(pfl[ky]);
                float rt = u2f(pfr[ky]);
                float w0=pw9[ky*3], w1=pw9[ky*3+1], wv2=pw9[ky*3+2];
                #pragma unroll
                for (int i=0;i<16;++i){
                    float l  = i ? m[i-1] : lf;
                    float r_ = (i==15) ? rt : m[i+1];
                    acc[i] = fmaf(w0,l, fmaf(w1,m[i], fmaf(wv2,r_,acc[i])));
                }
            }
            #pragma unroll
            for (int i=0;i<8;++i){
                o0v[i] = f2u(fgelu(acc[i]+pbj));
                o1v[i] = f2u(fgelu(acc[8+i]+pbj));
            }
        }
        if (cc < 3) LOADCHUNK(cc+1);
        *(ushort8*)(ub + cj*260 + pxo)     = o0v;
        *(ushort8*)(ub + cj*260 + pxo + 8) = o1v;
        __syncthreads();
        {
            bf16x8 A1g[2][2];
            #pragma unroll
            for (int t2=0;t2<2;++t2)
                #pragma unroll
                for (int kh=0;kh<2;++kh){
                    int combo = (cc*2+t2)*2+kh;
                    ushort8 u = *reinterpret_cast<const ushort8*>(buf1 + (combo*64 + lane)*8);
                    bf16x8 f;
                    #pragma unroll
                    for (int j=0;j<8;++j) f[j]=(short)u[j];
                    A1g[t2][kh]=f;
                }
            bf16x8 A2[4];
            #pragma unroll
            for (int ot=0;ot<4;++ot){
                int combo = cc*4+ot;
                ushort8 u = *reinterpret_cast<const ushort8*>(buf2 + (combo*64 + lane)*8);
                bf16x8 f;
                #pragma unroll
                for (int j=0;j<8;++j) f[j]=(short)u[j];
                A2[ot] = f;
            }
            #pragma unroll
            for (int q=0;q<2;++q){
                int px = (wv*2+q)*16 + col;
                bf16x8 B0 = *(const bf16x8*)((char*)xs + px*128 + ((g*16) ^ ((px&7)<<4)));
                bf16x8 B1 = *(const bf16x8*)((char*)xs + px*128 + ((64 + g*16) ^ ((px&7)<<4)));
                f32x4 D0 = *(const f32x4*)(l1b + 128 + cc*32 + g*4);
                f32x4 D1 = *(const f32x4*)(l1b + 128 + cc*32 + 16 + g*4);
                D0 = __builtin_amdgcn_mfma_f32_16x16x32_bf16(A1g[0][0], B0, D0, 0,0,0);
                D0 = __builtin_amdgcn_mfma_f32_16x16x32_bf16(A1g[0][1], B1, D0, 0,0,0);
                D1 = __builtin_amdgcn_mfma_f32_16x16x32_bf16(A1g[1][0], B0, D1, 0,0,0);
                D1 = __builtin_amdgcn_mfma_f32_16x16x32_bf16(A1g[1][1], B1, D1, 0,0,0);
                bf16x8 Bg;
                #pragma unroll
                for (int j=0;j<4;++j){
                    float u0 = u2f(ub[(g*4+j)*260 + px]);
                    float u1 = u2f(ub[(16+g*4+j)*260 + px]);
                    Bg[j]   = (short)f2u(u0 * fgelu(D0[j]));
                    Bg[4+j] = (short)f2u(u1 * fgelu(D1[j]));
                }
                #pragma unroll
                for (int ot=0;ot<4;++ot)
                    Dx[q][ot] = __builtin_amdgcn_mfma_f32_16x16x32_bf16(A2[ot], Bg, Dx[q][ot], 0,0,0);
            }
        }
    }
    __syncthreads();
    #pragma unroll
    for (int q=0;q<2;++q)
        #pragma unroll
        for (int ot=0;ot<4;++ot)
            #pragma unroll
            for (int rr=0;rr<4;++rr)
                ubuf[(ot*16 + g*4 + rr)*136 + (wv*2+q)*16 + col] = f2u(Dx[q][ot][rr]);
    __syncthreads();
    {
        int ch  = t >> 2;
        int pxb = (t & 3) * 32;
        size_t off = ((size_t)(b*CC + ch))*HWS + (size_t)y*WW + pxb;
        #pragma unroll
        for (int i=0;i<4;++i){
            ushort8 dv = *reinterpret_cast<const ushort8*>(ubuf + ch*136 + pxb + i*8);
            ushort8 vv = *reinterpret_cast<const ushort8*>(v + off + i*8);
            ushort8 ov;
            float rv[8];
            #pragma unroll
            for (int j=0;j<8;++j){
                rv[j] = u2f(dv[j]) + u2f(vv[j]);
                ov[j] = f2u(rv[j]);
            }
            *reinterpret_cast<ushort8*>(xout + off + i*8) = ov;
            if (xinit){
                float4v x0 = *reinterpret_cast<const float4v*>(xinit + off + i*8);
                float4v x1v = *reinterpret_cast<const float4v*>(xinit + off + i*8 + 4);
                ushort8 sv;
                sv[0]=f2u(rv[0]+x0.x); sv[1]=f2u(rv[1]+x0.y);
                sv[2]=f2u(rv[2]+x0.z); sv[3]=f2u(rv[3]+x0.w);
                sv[4]=f2u(rv[4]+x1v.x); sv[5]=f2u(rv[5]+x1v.y);
                sv[6]=f2u(rv[6]+x1v.z); sv[7]=f2u(rv[7]+x1v.w);
                *reinterpret_cast<ushort8*>(xsum + off + i*8) = sv;
            }
        }
    }
}

// ---------------------------------------------------------------- final conv (64->1, 3x3), 4 px/thread (R16)
__global__ __launch_bounds__(256) void k_final(
    const bf16* __restrict__ s, const float* __restrict__ w,
    const float* __restrict__ bias, float* __restrict__ out)
{
    int gid = blockIdx.x*256 + threadIdx.x;
    int b = gid >> 12;
    int sp4 = (gid & 4095) << 2;
    int y = sp4 >> 7, x0 = sp4 & 127;
    const bf16* sb = s + (size_t)b*CC*HWS;
    float acc[4];
    #pragma unroll
    for (int i=0;i<4;++i) acc[i] = bias[0];

    #pragma unroll 1
    for (int c=0;c<CC;++c){
        const bf16* ip = sb + (size_t)c*HWS;
        const float* wp = w + (size_t)c*9;
        #pragma unroll
        for (int ky=0;ky<3;++ky){
            int yy = y + ky - 1;
            float xv[6];
            if (yy >= 0 && yy < HH){
                const bf16* rp = ip + yy*WW + x0;
                ushort4v mv = *reinterpret_cast<const ushort4v*>(rp);
                xv[1]=u2f(mv[0]); xv[2]=u2f(mv[1]); xv[3]=u2f(mv[2]); xv[4]=u2f(mv[3]);
                xv[0] = (x0>0)    ? b2f(rp[-1]) : 0.f;
                xv[5] = (x0+4<WW) ? b2f(rp[4])  : 0.f;
            } else {
                #pragma unroll
                for (int i=0;i<6;++i) xv[i] = 0.f;
            }
            float w0 = wp[ky*3+0], w1 = wp[ky*3+1], w2 = wp[ky*3+2];
            #pragma unroll
            for (int i=0;i<4;++i)
                acc[i] = fmaf(w0, xv[i],
                         fmaf(w1, xv[i+1],
                         fmaf(w2, xv[i+2], acc[i])));
        }
    }
    float4v ov; ov.x=acc[0]; ov.y=acc[1]; ov.z=acc[2]; ov.w=acc[3];
    *reinterpret_cast<float4v*>(out + (size_t)gid*4) = ov;
}

// ---------------------------------------------------------------- launch
extern "C" void kernel_launch(void* const* d_in, const int* in_sizes, int n_in,
                              void* d_out, int out_size, void* d_ws, size_t ws_size,
                              hipStream_t stream)
{
    const float* x    = (const float*)d_in[0];
    const float* wz1  = (const float*)d_in[1];
    const float* bz1  = (const float*)d_in[2];
    const float* wz2  = (const float*)d_in[3];
    const float* bz2  = (const float*)d_in[4];
    const float* wf1  = (const float*)d_in[5];
    const float* bf1  = (const float*)d_in[6];
    const float* wf2  = (const float*)d_in[7];
    const float* bf2  = (const float*)d_in[8];
    const float* pw   = (const float*)d_in[9];
    const float* l1w  = (const float*)d_in[10];
    const float* l1b  = (const float*)d_in[11];
    const float* dww  = (const float*)d_in[12];
    const float* dwb  = (const float*)d_in[13];
    const float* l2w  = (const float*)d_in[14];
    const float* l2b  = (const float*)d_in[15];
    const float* ow   = (const float*)d_in[16];
    const float* obb  = (const float*)d_in[17];

    char* ws = (char*)d_ws;
    bf16* xc    = (bf16*)(ws);                    // 33,554,432 B
    bf16* v     = (bf16*)(ws + 33554432);         // 33,554,432 B
    bf16* x1    = (bf16*)(ws + 67108864);         //  8,388,608 B
    bf16* xsumb = (bf16*)(ws + 75497472);         // 33,554,432 B
    bf16* h1buf = (bf16*)(ws + 109051904);        // 67,108,864 B
    bf16* wfrag = (bf16*)(ws + 176160768);        // 3 x 32 KB

    k_wprep<<<3, 256, 0, stream>>>(l1w, l2w, wfrag);
    for (int l=0;l<3;++l){
        if (l == 0)
            k_gate<1><<<512, 256, 0, stream>>>(x, nullptr,
                wz1 + l*CC*CC, bz1 + l*CC, wz2 + l*CC*CC, bz2 + l*CC,
                wf1 + l*CC*CC, bf1 + l*CC, wf2 + l*CC*CC, bf2 + l*CC, v);
        else
            k_gate<0><<<512, 256, 0, stream>>>(nullptr, xc,
                wz1 + l*CC*CC, bz1 + l*CC, wz2 + l*CC*CC, bz2 + l*CC,
                wf1 + l*CC*CC, bf1 + l*CC, wf2 + l*CC*CC, bf2 + l*CC, v);
        k_pl1  <<<NPIX/256, 256, 0, stream>>>(v, pw + l*DCC*DCC*9,
                l1w + l*CC*256, l1b + l*256, x1, h1buf);
        k_dwA  <<<BB*HH, 256, 0, stream>>>(x1, v, h1buf, wfrag + (size_t)l*16384,
                l1b + l*256,
                dww + l*HIDN*9, dwb + l*HIDN,
                l2b + l*CC,
                xc, (l==2) ? x : nullptr, xsumb);
    }
    k_final<<<NPIX/(256*4), 256, 0, stream>>>(xsumb, ow, obb, (float*)d_out);
}

// Round 22
// 620.108 us; speedup vs baseline: 1.1969x; 1.0712x over previous
//
#include <hip/hip_runtime.h>
#include <hip/hip_bf16.h>

#define CC 64
#define HIDN 128
#define DCC 16
#define HH 128
#define WW 128
#define HWS (HH*WW)        // 16384
#define BB 16
#define NPIX (BB*HWS)      // 262144

typedef __hip_bfloat16 bf16;
typedef __attribute__((ext_vector_type(8))) unsigned short ushort8;
typedef __attribute__((ext_vector_type(4))) unsigned short ushort4v;
typedef __attribute__((ext_vector_type(4))) float float4v;
typedef __attribute__((ext_vector_type(8))) short bf16x8;
typedef __attribute__((ext_vector_type(4))) float f32x4;

__device__ __forceinline__ float rcp_fast(float x){ return __builtin_amdgcn_rcpf(x); }
__device__ __forceinline__ float ftanh(float x){
    float e = __expf(2.f*x);
    return 1.f - 2.f*rcp_fast(e + 1.f);
}
__device__ __forceinline__ float fsig(float x){
    return rcp_fast(1.f + __expf(-x));
}
__device__ __forceinline__ float fgelu(float x){
    return x * fsig(x*(1.5957691216f + 0.07135481283f*x*x));
}
__device__ __forceinline__ float b2f(bf16 v){ return __bfloat162float(v); }
__device__ __forceinline__ float u2f(unsigned short u){
    unsigned v = ((unsigned)u) << 16; return __uint_as_float(v);
}
__device__ __forceinline__ unsigned short f2u(float f){
    bf16 h = __float2bfloat16(f);
    return *reinterpret_cast<unsigned short*>(&h);
}
__device__ __forceinline__ bf16x8 ldfrag(const unsigned short* base, int combo, int lane){
    ushort8 u = *reinterpret_cast<const ushort8*>(base + (combo*64 + lane)*8);
    bf16x8 f;
    #pragma unroll
    for (int j=0;j<8;++j) f[j]=(short)u[j];
    return f;
}

// wfrag per-layer layout (bf16 elems):
//   buf1 [ 0..8191]   dwA lazy-h2 frags (16 combos)
//   buf2 [ 8192..16383] dwA lin2 frags (16 combos)
//   buf3 [16384..24575] pl1 h1-half frags (16 combos)
//   buf4 [24576..40959] gate frags: wz1,wf1 (psi1), wz2,wf2 (psi2) (32 combos)
#define WFRAG_STRIDE 40960

// ---------------------------------------------------------------- wprep
__global__ __launch_bounds__(256) void k_wprep(
    const float* __restrict__ l1w_all, const float* __restrict__ w2_all,
    const float* __restrict__ wz1_all, const float* __restrict__ wf1_all,
    const float* __restrict__ wz2_all, const float* __restrict__ wf2_all,
    bf16* __restrict__ frag_all)
{
    const int l = blockIdx.x;
    const float* l1w = l1w_all + (size_t)l*CC*256;
    const float* w2  = w2_all  + (size_t)l*HIDN*CC;
    const float* gw0 = wz1_all + (size_t)l*CC*CC;
    const float* gw1 = wf1_all + (size_t)l*CC*CC;
    const float* gw2 = wz2_all + (size_t)l*CC*CC;
    const float* gw3 = wf2_all + (size_t)l*CC*CC;
    unsigned short* buf1 = (unsigned short*)(frag_all + (size_t)l*WFRAG_STRIDE);
    unsigned short* buf2 = buf1 + 8192;
    unsigned short* buf3 = buf2 + 8192;
    unsigned short* buf4 = buf3 + 8192;
    const int t = threadIdx.x;
    const int lane = t & 63;
    const int col = lane & 15;
    const int g = lane >> 4;
    const int grp = t >> 6;

    // buf1: dwA lazy-h2, combo=(cc*2+t2)*2+kh
    for (int combo = grp; combo < 16; combo += 4){
        int cc = combo >> 2, t2 = (combo>>1)&1, kh = combo&1;
        #pragma unroll
        for (int j=0;j<8;++j){
            int cin = kh*32 + g*8 + j;
            buf1[(combo*64 + lane)*8 + j] =
                f2u(l1w[cin*256 + 128 + cc*32 + t2*16 + col]);
        }
    }
    // buf2: dwA lin2, combo=cc*4+ot
    for (int combo = grp; combo < 16; combo += 4){
        int cc = combo >> 2, ot = combo & 3;
        #pragma unroll
        for (int j=0;j<8;++j){
            int k = cc*32 + ((j>>2)<<4) + (g<<2) + (j&3);
            buf2[(combo*64 + lane)*8 + j] = f2u(w2[k*64 + ot*16 + col]);
        }
    }
    // buf3: pl1 h1-half, combo=(oc*2+t2)*2+kh
    for (int combo = grp; combo < 16; combo += 4){
        int oc = combo >> 2, t2 = (combo>>1)&1, kh = combo&1;
        #pragma unroll
        for (int j=0;j<8;++j){
            int cin = kh*32 + g*8 + j;
            buf3[(combo*64 + lane)*8 + j] =
                f2u(l1w[cin*256 + oc*32 + t2*16 + col]);
        }
    }
    // buf4: gate, combo=m*8+ot*2+kh; m=0,1 psi1; m=2,3 psi2
    for (int combo = grp; combo < 32; combo += 4){
        int m = combo >> 3, ot = (combo>>1)&3, kh = combo&1;
        const float* W = (m==0)?gw0:(m==1)?gw1:(m==2)?gw2:gw3;
        #pragma unroll
        for (int j=0;j<8;++j){
            int off;
            if (m < 2) off = kh*32 + g*8 + j;                       // psi1
            else       off = kh*32 + g*4 + (j&3) + ((j>>2)<<4);     // psi2
            buf4[(combo*64 + lane)*8 + j] = f2u(W[(ot*16+col)*64 + off]);
        }
    }
}

// ---------------------------------------------------------------- gate (512-px blocks, MFMA, zero-shuffle chain; packed frags)
template<int F32>
__global__ __launch_bounds__(256,2) void k_gate(
    const float* __restrict__ xf, const bf16* __restrict__ xb,
    const bf16* __restrict__ gfrag,
    const float* __restrict__ bz1, const float* __restrict__ bz2,
    const float* __restrict__ bf1, const float* __restrict__ bf2,
    bf16* __restrict__ vout)
{
    __shared__ __align__(16) unsigned short xs[512*64];   // 64 KB
    const int t = threadIdx.x;
    const int lane = t & 63;
    const int wv = t >> 6;
    const int g = lane >> 4;
    const int blk = blockIdx.x;
    const int b = blk >> 5;
    const int sp0 = (blk & 31) << 9;

    {
        const int ch = t & 63;
        const int wg = t >> 6;
        const size_t base = ((size_t)b*CC + ch)*HWS + sp0;
        #pragma unroll
        for (int i=0;i<16;++i){
            int bufpx = (wg*16 + i) << 3;
            ushort8 val;
            if (F32){
                float4v a = *reinterpret_cast<const float4v*>(xf + base + bufpx);
                float4v c = *reinterpret_cast<const float4v*>(xf + base + bufpx + 4);
                val[0]=f2u(a.x); val[1]=f2u(a.y); val[2]=f2u(a.z); val[3]=f2u(a.w);
                val[4]=f2u(c.x); val[5]=f2u(c.y); val[6]=f2u(c.z); val[7]=f2u(c.w);
            } else {
                val = *reinterpret_cast<const ushort8*>(xb + base + bufpx);
            }
            #pragma unroll
            for (int j=0;j<8;++j){
                int px = bufpx + j;
                *(unsigned short*)((char*)xs + px*128 + ((ch*2) ^ ((px&7)<<4))) = val[j];
            }
        }
    }

    const unsigned short* gbuf = (const unsigned short*)gfrag;
    bf16x8 Az1[4][2], Af1[4][2], Az2[4][2], Af2[4][2];
    #pragma unroll
    for (int ot=0; ot<4; ++ot)
        #pragma unroll
        for (int kh=0; kh<2; ++kh){
            Az1[ot][kh] = ldfrag(gbuf, 0*8 + ot*2 + kh, lane);
            Af1[ot][kh] = ldfrag(gbuf, 1*8 + ot*2 + kh, lane);
            Az2[ot][kh] = ldfrag(gbuf, 2*8 + ot*2 + kh, lane);
            Af2[ot][kh] = ldfrag(gbuf, 3*8 + ot*2 + kh, lane);
        }
    __syncthreads();

    bf16* vb = vout + (size_t)b*CC*HWS;
    const int col = lane & 15;

    for (int it = wv; it < 32; it += 4){
        const int lpx = it*16 + col;
        const int px = sp0 + lpx;
        bf16x8 Bx[2];
        Bx[0] = *(const bf16x8*)((char*)xs + lpx*128 + ((g*16) ^ ((lpx&7)<<4)));
        Bx[1] = *(const bf16x8*)((char*)xs + lpx*128 + ((64 + g*16) ^ ((lpx&7)<<4)));
        f32x4 Dz[4], Df[4];
        #pragma unroll
        for (int ot=0; ot<4; ++ot){
            Dz[ot] = *(const f32x4*)(bz1 + ot*16 + g*4);
            Df[ot] = *(const f32x4*)(bf1 + ot*16 + g*4);
        }
        #pragma unroll
        for (int kh=0; kh<2; ++kh)
            #pragma unroll
            for (int ot=0; ot<4; ++ot){
                Dz[ot] = __builtin_amdgcn_mfma_f32_16x16x32_bf16(Az1[ot][kh], Bx[kh], Dz[ot], 0,0,0);
                Df[ot] = __builtin_amdgcn_mfma_f32_16x16x32_bf16(Af1[ot][kh], Bx[kh], Df[ot], 0,0,0);
            }
        #pragma unroll
        for (int ot=0; ot<4; ++ot)
            #pragma unroll
            for (int r=0; r<4; ++r){
                Dz[ot][r] = ftanh(Dz[ot][r]);
                Df[ot][r] = ftanh(Df[ot][r]);
            }
        bf16x8 Bz[2], Bf[2];
        #pragma unroll
        for (int kh=0; kh<2; ++kh)
            #pragma unroll
            for (int j=0; j<4; ++j){
                Bz[kh][j]   = (short)f2u(Dz[2*kh][j]);
                Bz[kh][4+j] = (short)f2u(Dz[2*kh+1][j]);
                Bf[kh][j]   = (short)f2u(Df[2*kh][j]);
                Bf[kh][4+j] = (short)f2u(Df[2*kh+1][j]);
            }
        f32x4 Ez[4], Ef[4];
        #pragma unroll
        for (int ot=0; ot<4; ++ot){
            Ez[ot] = *(const f32x4*)(bz2 + ot*16 + g*4);
            Ef[ot] = *(const f32x4*)(bf2 + ot*16 + g*4);
        }
        #pragma unroll
        for (int kh=0; kh<2; ++kh)
            #pragma unroll
            for (int ot=0; ot<4; ++ot){
                Ez[ot] = __builtin_amdgcn_mfma_f32_16x16x32_bf16(Az2[ot][kh], Bz[kh], Ez[ot], 0,0,0);
                Ef[ot] = __builtin_amdgcn_mfma_f32_16x16x32_bf16(Af2[ot][kh], Bf[kh], Ef[ot], 0,0,0);
            }
        #pragma unroll
        for (int ot=0; ot<4; ++ot)
            #pragma unroll
            for (int r=0; r<4; ++r){
                float Zv = ftanh(Ez[ot][r]);
                float Fv = fsig(Ef[ot][r]);
                *reinterpret_cast<unsigned short*>(vb + (size_t)(ot*16+g*4+r)*HWS + px)
                    = f2u((1.f - Fv)*Zv);
            }
    }
}

// ---------------------------------------------------------------- pl1: pconv(16->16,3x3) FUSED with lin1h (packed frags)
__global__ __launch_bounds__(256) void k_pl1(
    const bf16* __restrict__ v, const float* __restrict__ pw,
    const bf16* __restrict__ plfrag, const float* __restrict__ l1b,
    bf16* __restrict__ x1out, bf16* __restrict__ h1out)
{
    __shared__ __align__(16) unsigned short xs[256*64];   // 32 KB
    __shared__ __align__(16) unsigned short vh[16][4][128]; // 16 KB
    __shared__ __align__(16) unsigned short tr[4][32*66]; // 16.5 KB, wave-private
    const int t = threadIdx.x;
    const int lane = t & 63;
    const int wv = t >> 6;
    const int col = lane & 15;
    const int g = lane >> 4;
    const int blk = blockIdx.x;         // 1024 blocks
    const int b = blk >> 6;
    const int y0 = (blk & 63) << 1;     // 2 rows
    const int sp0 = y0 * WW;

    {
        const int ch = t & 63;
        const int wg = t >> 6;
        if (ch < DCC){
            int gy = y0 - 1 + wg;
            unsigned short* dst = &vh[ch][wg][0];
            if (gy >= 0 && gy < HH){
                const bf16* src = v + ((size_t)b*CC + ch)*HWS + (size_t)gy*WW;
                #pragma unroll
                for (int i=0;i<16;++i)
                    *reinterpret_cast<ushort8*>(dst + i*8) =
                        *reinterpret_cast<const ushort8*>(src + i*8);
            } else {
                #pragma unroll
                for (int i=0;i<16;++i){
                    ushort8 z;
                    #pragma unroll
                    for (int j=0;j<8;++j) z[j]=0;
                    *reinterpret_cast<ushort8*>(dst + i*8) = z;
                }
            }
        } else {
            const bf16* src = v + ((size_t)b*CC + ch)*HWS + sp0;
            #pragma unroll
            for (int i=0;i<8;++i){
                int bufpx = wg*64 + i*8;
                ushort8 val = *reinterpret_cast<const ushort8*>(src + bufpx);
                #pragma unroll
                for (int j=0;j<8;++j){
                    int px = bufpx + j;
                    *(unsigned short*)((char*)xs + px*128 + ((ch*2) ^ ((px&7)<<4))) = val[j];
                }
            }
        }
    }
    __syncthreads();

    {
        const int oc = t >> 4;
        const int px0 = (t & 15) << 3;
        float acc[2][8];
        #pragma unroll
        for (int r=0;r<2;++r)
            #pragma unroll
            for (int i=0;i<8;++i) acc[r][i]=0.f;
        #pragma unroll 1
        for (int ic=0; ic<DCC; ++ic){
            float m[4][10];
            #pragma unroll
            for (int row=0;row<4;++row){
                const unsigned short* rp = &vh[ic][row][px0];
                ushort8 mv = *reinterpret_cast<const ushort8*>(rp);
                #pragma unroll
                for (int i=0;i<8;++i) m[row][i+1] = u2f(mv[i]);
                m[row][0] = (px0>0)    ? u2f(rp[-1]) : 0.f;
                m[row][9] = (px0+8<WW) ? u2f(rp[8])  : 0.f;
            }
            const float* wp = pw + (size_t)(oc*DCC+ic)*9;
            #pragma unroll
            for (int ky=0;ky<3;++ky){
                float w0 = wp[ky*3+0], w1 = wp[ky*3+1], w2 = wp[ky*3+2];
                #pragma unroll
                for (int r=0;r<2;++r)
                    #pragma unroll
                    for (int i=0;i<8;++i)
                        acc[r][i] = fmaf(w0, m[r+ky][i],
                                    fmaf(w1, m[r+ky][i+1],
                                    fmaf(w2, m[r+ky][i+2], acc[r][i])));
            }
        }
        #pragma unroll
        for (int r=0;r<2;++r){
            ushort8 ov;
            #pragma unroll
            for (int i=0;i<8;++i){
                unsigned short uu = f2u(acc[r][i]);
                ov[i] = uu;
                int px = r*128 + px0 + i;
                *(unsigned short*)((char*)xs + px*128 + ((oc*2) ^ ((px&7)<<4))) = uu;
            }
            *reinterpret_cast<ushort8*>(x1out + ((size_t)b*DCC + oc)*HWS
                                        + (size_t)(y0+r)*WW + px0) = ov;
        }
    }
    __syncthreads();

    const unsigned short* pbuf = (const unsigned short*)plfrag;
    unsigned short* trw = &tr[wv][0];
    const int lpx0 = wv*64;

    #pragma unroll 1
    for (int oc=0; oc<4; ++oc){
        bf16x8 A1[2][2];
        #pragma unroll
        for (int t2=0;t2<2;++t2)
            #pragma unroll
            for (int kh=0;kh<2;++kh)
                A1[t2][kh] = ldfrag(pbuf, (oc*2+t2)*2+kh, lane);
        #pragma unroll
        for (int lt=0;lt<4;++lt){
            int px = lpx0 + lt*16 + col;
            bf16x8 B0 = *(const bf16x8*)((char*)xs + px*128 + ((g*16) ^ ((px&7)<<4)));
            bf16x8 B1 = *(const bf16x8*)((char*)xs + px*128 + ((64 + g*16) ^ ((px&7)<<4)));
            f32x4 D0 = *(const f32x4*)(l1b + oc*32 + g*4);
            f32x4 D1 = *(const f32x4*)(l1b + oc*32 + 16 + g*4);
            D0 = __builtin_amdgcn_mfma_f32_16x16x32_bf16(A1[0][0], B0, D0, 0,0,0);
            D0 = __builtin_amdgcn_mfma_f32_16x16x32_bf16(A1[0][1], B1, D0, 0,0,0);
            D1 = __builtin_amdgcn_mfma_f32_16x16x32_bf16(A1[1][0], B0, D1, 0,0,0);
            D1 = __builtin_amdgcn_mfma_f32_16x16x32_bf16(A1[1][1], B1, D1, 0,0,0);
            int lp = lt*16 + col;
            #pragma unroll
            for (int rr=0;rr<4;++rr){
                trw[(g*4+rr)*66 + lp]    = f2u(fgelu(D0[rr]));
                trw[(16+g*4+rr)*66 + lp] = f2u(fgelu(D1[rr]));
            }
        }
        {
            int ch2 = lane >> 1;
            int half = lane & 1;
            const unsigned short* srcp = trw + ch2*66 + half*32;
            bf16* dst = h1out + ((size_t)(b*HIDN + oc*32 + ch2))*HWS + sp0 + lpx0 + half*32;
            #pragma unroll
            for (int i=0;i<4;++i){
                ushort8 u8 = *reinterpret_cast<const ushort8*>(srcp + i*8);
                *reinterpret_cast<ushort8*>(dst + i*8) = u8;
            }
        }
    }
}

// ---------------------------------------------------------------- dwA: dwconv(h1)+gelu + lazy-h2 + gate + lin2 fused (R15/R16 version)
__global__ __launch_bounds__(256) void k_dwA(
    const bf16* __restrict__ x1, const bf16* __restrict__ v,
    const bf16* __restrict__ h1, const bf16* __restrict__ wfrag,
    const float* __restrict__ l1b,
    const float* __restrict__ dww, const float* __restrict__ dwb,
    const float* __restrict__ l2b,
    bf16* __restrict__ xout,
    const float* __restrict__ xinit,   // non-null on last layer
    bf16* __restrict__ xsum)
{
    __shared__ __align__(16) unsigned short xs[128*64];    // 16 KB (center row)
    __shared__ __align__(16) unsigned short ubuf[2*8320];  // 33.3 KB
    const int t = threadIdx.x;
    const int lane = t & 63;
    const int wv = t >> 6;
    const int col = lane & 15;
    const int g = lane >> 4;
    const int blk0 = blockIdx.x;          // 2048 blocks
    const int blk = (blk0 & 7)*256 + (blk0 >> 3);   // XCD-contiguous rows
    const int b = blk >> 7;
    const int y = blk & 127;

    const int cj  = (t>>3) & 31;     // dw channel within chunk
    const int pxo = (t & 7) << 4;    // dw 16-px group

    const unsigned short* buf1 = (const unsigned short*)wfrag;
    const unsigned short* buf2 = buf1 + 8192;

    ushort8 pfa[3], pfb[3];
    unsigned short pfl[3], pfr[3];
    float pw9[9], pbj;
    auto LOADCHUNK = [&](int cc){
        int chg = cc*32 + cj;
        const bf16* h1p = h1 + ((size_t)(b*HIDN + chg))*HWS;
        #pragma unroll
        for (int ky=0; ky<3; ++ky){
            int gy = y + ky - 1;
            if (gy >= 0 && gy < HH){
                const bf16* rp = h1p + (size_t)gy*WW + pxo;
                pfa[ky] = *reinterpret_cast<const ushort8*>(rp);
                pfb[ky] = *reinterpret_cast<const ushort8*>(rp+8);
                pfl[ky] = (pxo>0)     ? *reinterpret_cast<const unsigned short*>(rp-1)  : 0;
                pfr[ky] = (pxo+16<WW) ? *reinterpret_cast<const unsigned short*>(rp+16) : 0;
            } else {
                #pragma unroll
                for (int i=0;i<8;++i){ pfa[ky][i]=0; pfb[ky][i]=0; }
                pfl[ky]=0; pfr[ky]=0;
            }
        }
        #pragma unroll
        for (int i=0;i<9;++i) pw9[i] = dww[chg*9+i];
        pbj = dwb[chg];
    };

    LOADCHUNK(0);

    {   // stage x-cat center row: 64ch x 128px
        const int ch = t & 63;
        const int wg = t >> 6;
        const bf16* src = (ch < DCC) ? x1 + ((size_t)b*DCC + ch)*HWS
                                     : v  + ((size_t)b*CC  + ch)*HWS;
        #pragma unroll
        for (int i=0;i<2;++i){
            int bufpx = (wg*2 + i) << 3;
            ushort8 val = *reinterpret_cast<const ushort8*>(src + (size_t)y*WW + bufpx);
            #pragma unroll
            for (int j=0;j<8;++j){
                int px = bufpx + j;
                *(unsigned short*)((char*)xs + px*128 + ((ch*2) ^ ((px&7)<<4))) = val[j];
            }
        }
    }
    __syncthreads();

    f32x4 Dx[2][4];
    #pragma unroll
    for (int q=0;q<2;++q)
        #pragma unroll
        for (int ot=0;ot<4;++ot)
            Dx[q][ot] = *(const f32x4*)(l2b + ot*16 + g*4);

    #pragma unroll 1
    for (int cc=0; cc<4; ++cc){
        unsigned short* ub = ubuf + (cc&1)*8320;
        ushort8 o0v, o1v;
        {
            float acc[16];
            #pragma unroll
            for (int i=0;i<16;++i) acc[i]=0.f;
            #pragma unroll
            for (int ky=0; ky<3; ++ky){
                float m[16];
                #pragma unroll
                for (int i=0;i<8;++i){ m[i]=u2f(pfa[ky][i]); m[8+i]=u2f(pfb[ky][i]); }
                float lf = u2f(pfl[ky]);
                float rt = u2f(pfr[ky]);
                float w0=pw9[ky*3], w1=pw9[ky*3+1], wv2=pw9[ky*3+2];
                #pragma unroll
                for (int i=0;i<16;++i){
                    float l  = i ? m[i-1] : lf;
                    float r_ = (i==15) ? rt : m[i+1];
                    acc[i] = fmaf(w0,l, fmaf(w1,m[i], fmaf(wv2,r_,acc[i])));
                }
            }
            #pragma unroll
            for (int i=0;i<8;++i){
                o0v[i] = f2u(fgelu(acc[i]+pbj));
                o1v[i] = f2u(fgelu(acc[8+i]+pbj));
            }
        }
        if (cc < 3) LOADCHUNK(cc+1);
        *(ushort8*)(ub + cj*260 + pxo)     = o0v;
        *(ushort8*)(ub + cj*260 + pxo + 8) = o1v;
        __syncthreads();
        {
            bf16x8 A1g[2][2];
            #pragma unroll
            for (int t2=0;t2<2;++t2)
                #pragma unroll
                for (int kh=0;kh<2;++kh)
                    A1g[t2][kh] = ldfrag(buf1, (cc*2+t2)*2+kh, lane);
            bf16x8 A2[4];
            #pragma unroll
            for (int ot=0;ot<4;++ot)
                A2[ot] = ldfrag(buf2, cc*4+ot, lane);
            #pragma unroll
            for (int q=0;q<2;++q){
                int px = (wv*2+q)*16 + col;
                bf16x8 B0 = *(const bf16x8*)((char*)xs + px*128 + ((g*16) ^ ((px&7)<<4)));
                bf16x8 B1 = *(const bf16x8*)((char*)xs + px*128 + ((64 + g*16) ^ ((px&7)<<4)));
                f32x4 D0 = *(const f32x4*)(l1b + 128 + cc*32 + g*4);
                f32x4 D1 = *(const f32x4*)(l1b + 128 + cc*32 + 16 + g*4);
                D0 = __builtin_amdgcn_mfma_f32_16x16x32_bf16(A1g[0][0], B0, D0, 0,0,0);
                D0 = __builtin_amdgcn_mfma_f32_16x16x32_bf16(A1g[0][1], B1, D0, 0,0,0);
                D1 = __builtin_amdgcn_mfma_f32_16x16x32_bf16(A1g[1][0], B0, D1, 0,0,0);
                D1 = __builtin_amdgcn_mfma_f32_16x16x32_bf16(A1g[1][1], B1, D1, 0,0,0);
                bf16x8 Bg;
                #pragma unroll
                for (int j=0;j<4;++j){
                    float u0 = u2f(ub[(g*4+j)*260 + px]);
                    float u1 = u2f(ub[(16+g*4+j)*260 + px]);
                    Bg[j]   = (short)f2u(u0 * fgelu(D0[j]));
                    Bg[4+j] = (short)f2u(u1 * fgelu(D1[j]));
                }
                #pragma unroll
                for (int ot=0;ot<4;++ot)
                    Dx[q][ot] = __builtin_amdgcn_mfma_f32_16x16x32_bf16(A2[ot], Bg, Dx[q][ot], 0,0,0);
            }
        }
    }
    __syncthreads();
    #pragma unroll
    for (int q=0;q<2;++q)
        #pragma unroll
        for (int ot=0;ot<4;++ot)
            #pragma unroll
            for (int rr=0;rr<4;++rr)
                ubuf[(ot*16 + g*4 + rr)*136 + (wv*2+q)*16 + col] = f2u(Dx[q][ot][rr]);
    __syncthreads();
    {
        int ch  = t >> 2;
        int pxb = (t & 3) * 32;
        size_t off = ((size_t)(b*CC + ch))*HWS + (size_t)y*WW + pxb;
        #pragma unroll
        for (int i=0;i<4;++i){
            ushort8 dv = *reinterpret_cast<const ushort8*>(ubuf + ch*136 + pxb + i*8);
            ushort8 vv = *reinterpret_cast<const ushort8*>(v + off + i*8);
            ushort8 ov;
            float rv[8];
            #pragma unroll
            for (int j=0;j<8;++j){
                rv[j] = u2f(dv[j]) + u2f(vv[j]);
                ov[j] = f2u(rv[j]);
            }
            *reinterpret_cast<ushort8*>(xout + off + i*8) = ov;
            if (xinit){
                float4v x0 = *reinterpret_cast<const float4v*>(xinit + off + i*8);
                float4v x1v = *reinterpret_cast<const float4v*>(xinit + off + i*8 + 4);
                ushort8 sv;
                sv[0]=f2u(rv[0]+x0.x); sv[1]=f2u(rv[1]+x0.y);
                sv[2]=f2u(rv[2]+x0.z); sv[3]=f2u(rv[3]+x0.w);
                sv[4]=f2u(rv[4]+x1v.x); sv[5]=f2u(rv[5]+x1v.y);
                sv[6]=f2u(rv[6]+x1v.z); sv[7]=f2u(rv[7]+x1v.w);
                *reinterpret_cast<ushort8*>(xsum + off + i*8) = sv;
            }
        }
    }
}

// ---------------------------------------------------------------- final conv (64->1, 3x3), 4 px/thread
__global__ __launch_bounds__(256) void k_final(
    const bf16* __restrict__ s, const float* __restrict__ w,
    const float* __restrict__ bias, float* __restrict__ out)
{
    int gid = blockIdx.x*256 + threadIdx.x;
    int b = gid >> 12;
    int sp4 = (gid & 4095) << 2;
    int y = sp4 >> 7, x0 = sp4 & 127;
    const bf16* sb = s + (size_t)b*CC*HWS;
    float acc[4];
    #pragma unroll
    for (int i=0;i<4;++i) acc[i] = bias[0];

    #pragma unroll 1
    for (int c=0;c<CC;++c){
        const bf16* ip = sb + (size_t)c*HWS;
        const float* wp = w + (size_t)c*9;
        #pragma unroll
        for (int ky=0;ky<3;++ky){
            int yy = y + ky - 1;
            float xv[6];
            if (yy >= 0 && yy < HH){
                const bf16* rp = ip + yy*WW + x0;
                ushort4v mv = *reinterpret_cast<const ushort4v*>(rp);
                xv[1]=u2f(mv[0]); xv[2]=u2f(mv[1]); xv[3]=u2f(mv[2]); xv[4]=u2f(mv[3]);
                xv[0] = (x0>0)    ? b2f(rp[-1]) : 0.f;
                xv[5] = (x0+4<WW) ? b2f(rp[4])  : 0.f;
            } else {
                #pragma unroll
                for (int i=0;i<6;++i) xv[i] = 0.f;
            }
            float w0 = wp[ky*3+0], w1 = wp[ky*3+1], w2 = wp[ky*3+2];
            #pragma unroll
            for (int i=0;i<4;++i)
                acc[i] = fmaf(w0, xv[i],
                         fmaf(w1, xv[i+1],
                         fmaf(w2, xv[i+2], acc[i])));
        }
    }
    float4v ov; ov.x=acc[0]; ov.y=acc[1]; ov.z=acc[2]; ov.w=acc[3];
    *reinterpret_cast<float4v*>(out + (size_t)gid*4) = ov;
}

// ---------------------------------------------------------------- launch
extern "C" void kernel_launch(void* const* d_in, const int* in_sizes, int n_in,
                              void* d_out, int out_size, void* d_ws, size_t ws_size,
                              hipStream_t stream)
{
    const float* x    = (const float*)d_in[0];
    const float* wz1  = (const float*)d_in[1];
    const float* bz1  = (const float*)d_in[2];
    const float* wz2  = (const float*)d_in[3];
    const float* bz2  = (const float*)d_in[4];
    const float* wf1  = (const float*)d_in[5];
    const float* bf1  = (const float*)d_in[6];
    const float* wf2  = (const float*)d_in[7];
    const float* bf2  = (const float*)d_in[8];
    const float* pw   = (const float*)d_in[9];
    const float* l1w  = (const float*)d_in[10];
    const float* l1b  = (const float*)d_in[11];
    const float* dww  = (const float*)d_in[12];
    const float* dwb  = (const float*)d_in[13];
    const float* l2w  = (const float*)d_in[14];
    const float* l2b  = (const float*)d_in[15];
    const float* ow   = (const float*)d_in[16];
    const float* obb  = (const float*)d_in[17];

    char* ws = (char*)d_ws;
    bf16* xc    = (bf16*)(ws);                    // 33,554,432 B
    bf16* v     = (bf16*)(ws + 33554432);         // 33,554,432 B
    bf16* x1    = (bf16*)(ws + 67108864);         //  8,388,608 B
    bf16* xsumb = (bf16*)(ws + 75497472);         // 33,554,432 B
    bf16* h1buf = (bf16*)(ws + 109051904);        // 67,108,864 B
    bf16* wfrag = (bf16*)(ws + 176160768);        // 3 x 80 KB

    k_wprep<<<3, 256, 0, stream>>>(l1w, l2w, wz1, wf1, wz2, wf2, wfrag);
    for (int l=0;l<3;++l){
        const bf16* wf = wfrag + (size_t)l*WFRAG_STRIDE;
        if (l == 0)
            k_gate<1><<<512, 256, 0, stream>>>(x, nullptr, wf + 24576,
                bz1 + l*CC, bz2 + l*CC, bf1 + l*CC, bf2 + l*CC, v);
        else
            k_gate<0><<<512, 256, 0, stream>>>(nullptr, xc, wf + 24576,
                bz1 + l*CC, bz2 + l*CC, bf1 + l*CC, bf2 + l*CC, v);
        k_pl1  <<<NPIX/256, 256, 0, stream>>>(v, pw + l*DCC*DCC*9,
                wf + 16384, l1b + l*256, x1, h1buf);
        k_dwA  <<<BB*HH, 256, 0, stream>>>(x1, v, h1buf, wf,
                l1b + l*256,
                dww + l*HIDN*9, dwb + l*HIDN,
                l2b + l*CC,
                xc, (l==2) ? x : nullptr, xsumb);
    }
    k_final<<<NPIX/(256*4), 256, 0, stream>>>(xsumb, ow, obb, (float*)d_out);
}

// Round 23
// 612.230 us; speedup vs baseline: 1.2124x; 1.0129x over previous
//
#include <hip/hip_runtime.h>
#include <hip/hip_bf16.h>

#define CC 64
#define HIDN 128
#define DCC 16
#define HH 128
#define WW 128
#define HWS (HH*WW)        // 16384
#define BB 16
#define NPIX (BB*HWS)      // 262144

typedef __hip_bfloat16 bf16;
typedef __attribute__((ext_vector_type(8))) unsigned short ushort8;
typedef __attribute__((ext_vector_type(4))) unsigned short ushort4v;
typedef __attribute__((ext_vector_type(4))) float float4v;
typedef __attribute__((ext_vector_type(8))) short bf16x8;
typedef __attribute__((ext_vector_type(4))) float f32x4;

__device__ __forceinline__ float rcp_fast(float x){ return __builtin_amdgcn_rcpf(x); }
__device__ __forceinline__ float ftanh(float x){
    float e = __expf(2.f*x);
    return 1.f - 2.f*rcp_fast(e + 1.f);
}
__device__ __forceinline__ float fsig(float x){
    return rcp_fast(1.f + __expf(-x));
}
__device__ __forceinline__ float fgelu(float x){
    return x * fsig(x*(1.5957691216f + 0.07135481283f*x*x));
}
__device__ __forceinline__ float b2f(bf16 v){ return __bfloat162float(v); }
__device__ __forceinline__ float u2f(unsigned short u){
    unsigned v = ((unsigned)u) << 16; return __uint_as_float(v);
}
__device__ __forceinline__ unsigned short f2u(float f){
    bf16 h = __float2bfloat16(f);
    return *reinterpret_cast<unsigned short*>(&h);
}
__device__ __forceinline__ bf16x8 ldfrag(const unsigned short* base, int combo, int lane){
    ushort8 u = *reinterpret_cast<const ushort8*>(base + (combo*64 + lane)*8);
    bf16x8 f;
    #pragma unroll
    for (int j=0;j<8;++j) f[j]=(short)u[j];
    return f;
}

// wfrag per-layer layout (bf16 elems):
//   buf1 [ 0..8191]   dwA lazy-h2 frags (16 combos)
//   buf2 [ 8192..16383] dwA lin2 frags (16 combos)
//   buf3 [16384..24575] pl1 h1-half frags (16 combos)
//   buf4 [24576..40959] gate frags: wz1,wf1 (psi1), wz2,wf2 (psi2) (32 combos)
#define WFRAG_STRIDE 40960

// ---------------------------------------------------------------- wprep
__global__ __launch_bounds__(256) void k_wprep(
    const float* __restrict__ l1w_all, const float* __restrict__ w2_all,
    const float* __restrict__ wz1_all, const float* __restrict__ wf1_all,
    const float* __restrict__ wz2_all, const float* __restrict__ wf2_all,
    bf16* __restrict__ frag_all)
{
    const int l = blockIdx.x;
    const float* l1w = l1w_all + (size_t)l*CC*256;
    const float* w2  = w2_all  + (size_t)l*HIDN*CC;
    const float* gw0 = wz1_all + (size_t)l*CC*CC;
    const float* gw1 = wf1_all + (size_t)l*CC*CC;
    const float* gw2 = wz2_all + (size_t)l*CC*CC;
    const float* gw3 = wf2_all + (size_t)l*CC*CC;
    unsigned short* buf1 = (unsigned short*)(frag_all + (size_t)l*WFRAG_STRIDE);
    unsigned short* buf2 = buf1 + 8192;
    unsigned short* buf3 = buf2 + 8192;
    unsigned short* buf4 = buf3 + 8192;
    const int t = threadIdx.x;
    const int lane = t & 63;
    const int col = lane & 15;
    const int g = lane >> 4;
    const int grp = t >> 6;

    for (int combo = grp; combo < 16; combo += 4){
        int cc = combo >> 2, t2 = (combo>>1)&1, kh = combo&1;
        #pragma unroll
        for (int j=0;j<8;++j){
            int cin = kh*32 + g*8 + j;
            buf1[(combo*64 + lane)*8 + j] =
                f2u(l1w[cin*256 + 128 + cc*32 + t2*16 + col]);
        }
    }
    for (int combo = grp; combo < 16; combo += 4){
        int cc = combo >> 2, ot = combo & 3;
        #pragma unroll
        for (int j=0;j<8;++j){
            int k = cc*32 + ((j>>2)<<4) + (g<<2) + (j&3);
            buf2[(combo*64 + lane)*8 + j] = f2u(w2[k*64 + ot*16 + col]);
        }
    }
    for (int combo = grp; combo < 16; combo += 4){
        int oc = combo >> 2, t2 = (combo>>1)&1, kh = combo&1;
        #pragma unroll
        for (int j=0;j<8;++j){
            int cin = kh*32 + g*8 + j;
            buf3[(combo*64 + lane)*8 + j] =
                f2u(l1w[cin*256 + oc*32 + t2*16 + col]);
        }
    }
    for (int combo = grp; combo < 32; combo += 4){
        int m = combo >> 3, ot = (combo>>1)&3, kh = combo&1;
        const float* W = (m==0)?gw0:(m==1)?gw1:(m==2)?gw2:gw3;
        #pragma unroll
        for (int j=0;j<8;++j){
            int off;
            if (m < 2) off = kh*32 + g*8 + j;                       // psi1
            else       off = kh*32 + g*4 + (j&3) + ((j>>2)<<4);     // psi2
            buf4[(combo*64 + lane)*8 + j] = f2u(W[(ot*16+col)*64 + off]);
        }
    }
}

// ---------------------------------------------------------------- gate (512-px blocks, MFMA, zero-shuffle chain; packed frags)
template<int F32>
__global__ __launch_bounds__(256,2) void k_gate(
    const float* __restrict__ xf, const bf16* __restrict__ xb,
    const bf16* __restrict__ gfrag,
    const float* __restrict__ bz1, const float* __restrict__ bz2,
    const float* __restrict__ bf1, const float* __restrict__ bf2,
    bf16* __restrict__ vout)
{
    __shared__ __align__(16) unsigned short xs[512*64];   // 64 KB
    const int t = threadIdx.x;
    const int lane = t & 63;
    const int wv = t >> 6;
    const int g = lane >> 4;
    const int blk = blockIdx.x;
    const int b = blk >> 5;
    const int sp0 = (blk & 31) << 9;

    {
        const int ch = t & 63;
        const int wg = t >> 6;
        const size_t base = ((size_t)b*CC + ch)*HWS + sp0;
        #pragma unroll
        for (int i=0;i<16;++i){
            int bufpx = (wg*16 + i) << 3;
            ushort8 val;
            if (F32){
                float4v a = *reinterpret_cast<const float4v*>(xf + base + bufpx);
                float4v c = *reinterpret_cast<const float4v*>(xf + base + bufpx + 4);
                val[0]=f2u(a.x); val[1]=f2u(a.y); val[2]=f2u(a.z); val[3]=f2u(a.w);
                val[4]=f2u(c.x); val[5]=f2u(c.y); val[6]=f2u(c.z); val[7]=f2u(c.w);
            } else {
                val = *reinterpret_cast<const ushort8*>(xb + base + bufpx);
            }
            #pragma unroll
            for (int j=0;j<8;++j){
                int px = bufpx + j;
                *(unsigned short*)((char*)xs + px*128 + ((ch*2) ^ ((px&7)<<4))) = val[j];
            }
        }
    }

    const unsigned short* gbuf = (const unsigned short*)gfrag;
    bf16x8 Az1[4][2], Af1[4][2], Az2[4][2], Af2[4][2];
    #pragma unroll
    for (int ot=0; ot<4; ++ot)
        #pragma unroll
        for (int kh=0; kh<2; ++kh){
            Az1[ot][kh] = ldfrag(gbuf, 0*8 + ot*2 + kh, lane);
            Af1[ot][kh] = ldfrag(gbuf, 1*8 + ot*2 + kh, lane);
            Az2[ot][kh] = ldfrag(gbuf, 2*8 + ot*2 + kh, lane);
            Af2[ot][kh] = ldfrag(gbuf, 3*8 + ot*2 + kh, lane);
        }
    __syncthreads();

    bf16* vb = vout + (size_t)b*CC*HWS;
    const int col = lane & 15;

    for (int it = wv; it < 32; it += 4){
        const int lpx = it*16 + col;
        const int px = sp0 + lpx;
        bf16x8 Bx[2];
        Bx[0] = *(const bf16x8*)((char*)xs + lpx*128 + ((g*16) ^ ((lpx&7)<<4)));
        Bx[1] = *(const bf16x8*)((char*)xs + lpx*128 + ((64 + g*16) ^ ((lpx&7)<<4)));
        f32x4 Dz[4], Df[4];
        #pragma unroll
        for (int ot=0; ot<4; ++ot){
            Dz[ot] = *(const f32x4*)(bz1 + ot*16 + g*4);
            Df[ot] = *(const f32x4*)(bf1 + ot*16 + g*4);
        }
        __builtin_amdgcn_s_setprio(1);
        #pragma unroll
        for (int kh=0; kh<2; ++kh)
            #pragma unroll
            for (int ot=0; ot<4; ++ot){
                Dz[ot] = __builtin_amdgcn_mfma_f32_16x16x32_bf16(Az1[ot][kh], Bx[kh], Dz[ot], 0,0,0);
                Df[ot] = __builtin_amdgcn_mfma_f32_16x16x32_bf16(Af1[ot][kh], Bx[kh], Df[ot], 0,0,0);
            }
        __builtin_amdgcn_s_setprio(0);
        #pragma unroll
        for (int ot=0; ot<4; ++ot)
            #pragma unroll
            for (int r=0; r<4; ++r){
                Dz[ot][r] = ftanh(Dz[ot][r]);
                Df[ot][r] = ftanh(Df[ot][r]);
            }
        bf16x8 Bz[2], Bf[2];
        #pragma unroll
        for (int kh=0; kh<2; ++kh)
            #pragma unroll
            for (int j=0; j<4; ++j){
                Bz[kh][j]   = (short)f2u(Dz[2*kh][j]);
                Bz[kh][4+j] = (short)f2u(Dz[2*kh+1][j]);
                Bf[kh][j]   = (short)f2u(Df[2*kh][j]);
                Bf[kh][4+j] = (short)f2u(Df[2*kh+1][j]);
            }
        f32x4 Ez[4], Ef[4];
        #pragma unroll
        for (int ot=0; ot<4; ++ot){
            Ez[ot] = *(const f32x4*)(bz2 + ot*16 + g*4);
            Ef[ot] = *(const f32x4*)(bf2 + ot*16 + g*4);
        }
        __builtin_amdgcn_s_setprio(1);
        #pragma unroll
        for (int kh=0; kh<2; ++kh)
            #pragma unroll
            for (int ot=0; ot<4; ++ot){
                Ez[ot] = __builtin_amdgcn_mfma_f32_16x16x32_bf16(Az2[ot][kh], Bz[kh], Ez[ot], 0,0,0);
                Ef[ot] = __builtin_amdgcn_mfma_f32_16x16x32_bf16(Af2[ot][kh], Bf[kh], Ef[ot], 0,0,0);
            }
        __builtin_amdgcn_s_setprio(0);
        #pragma unroll
        for (int ot=0; ot<4; ++ot)
            #pragma unroll
            for (int r=0; r<4; ++r){
                float Zv = ftanh(Ez[ot][r]);
                float Fv = fsig(Ef[ot][r]);
                *reinterpret_cast<unsigned short*>(vb + (size_t)(ot*16+g*4+r)*HWS + px)
                    = f2u((1.f - Fv)*Zv);
            }
    }
}

// ---------------------------------------------------------------- pl1: pconv(16->16,3x3) FUSED with lin1h (packed frags)
__global__ __launch_bounds__(256) void k_pl1(
    const bf16* __restrict__ v, const float* __restrict__ pw,
    const bf16* __restrict__ plfrag, const float* __restrict__ l1b,
    bf16* __restrict__ x1out, bf16* __restrict__ h1out)
{
    __shared__ __align__(16) unsigned short xs[256*64];   // 32 KB
    __shared__ __align__(16) unsigned short vh[16][4][128]; // 16 KB
    __shared__ __align__(16) unsigned short tr[4][32*66]; // 16.5 KB, wave-private
    const int t = threadIdx.x;
    const int lane = t & 63;
    const int wv = t >> 6;
    const int col = lane & 15;
    const int g = lane >> 4;
    const int blk = blockIdx.x;         // 1024 blocks
    const int b = blk >> 6;
    const int y0 = (blk & 63) << 1;     // 2 rows
    const int sp0 = y0 * WW;

    {
        const int ch = t & 63;
        const int wg = t >> 6;
        if (ch < DCC){
            int gy = y0 - 1 + wg;
            unsigned short* dst = &vh[ch][wg][0];
            if (gy >= 0 && gy < HH){
                const bf16* src = v + ((size_t)b*CC + ch)*HWS + (size_t)gy*WW;
                #pragma unroll
                for (int i=0;i<16;++i)
                    *reinterpret_cast<ushort8*>(dst + i*8) =
                        *reinterpret_cast<const ushort8*>(src + i*8);
            } else {
                #pragma unroll
                for (int i=0;i<16;++i){
                    ushort8 z;
                    #pragma unroll
                    for (int j=0;j<8;++j) z[j]=0;
                    *reinterpret_cast<ushort8*>(dst + i*8) = z;
                }
            }
        } else {
            const bf16* src = v + ((size_t)b*CC + ch)*HWS + sp0;
            #pragma unroll
            for (int i=0;i<8;++i){
                int bufpx = wg*64 + i*8;
                ushort8 val = *reinterpret_cast<const ushort8*>(src + bufpx);
                #pragma unroll
                for (int j=0;j<8;++j){
                    int px = bufpx + j;
                    *(unsigned short*)((char*)xs + px*128 + ((ch*2) ^ ((px&7)<<4))) = val[j];
                }
            }
        }
    }
    __syncthreads();

    {
        const int oc = t >> 4;
        const int px0 = (t & 15) << 3;
        float acc[2][8];
        #pragma unroll
        for (int r=0;r<2;++r)
            #pragma unroll
            for (int i=0;i<8;++i) acc[r][i]=0.f;
        #pragma unroll 1
        for (int ic=0; ic<DCC; ++ic){
            float m[4][10];
            #pragma unroll
            for (int row=0;row<4;++row){
                const unsigned short* rp = &vh[ic][row][px0];
                ushort8 mv = *reinterpret_cast<const ushort8*>(rp);
                #pragma unroll
                for (int i=0;i<8;++i) m[row][i+1] = u2f(mv[i]);
                m[row][0] = (px0>0)    ? u2f(rp[-1]) : 0.f;
                m[row][9] = (px0+8<WW) ? u2f(rp[8])  : 0.f;
            }
            const float* wp = pw + (size_t)(oc*DCC+ic)*9;
            #pragma unroll
            for (int ky=0;ky<3;++ky){
                float w0 = wp[ky*3+0], w1 = wp[ky*3+1], w2 = wp[ky*3+2];
                #pragma unroll
                for (int r=0;r<2;++r)
                    #pragma unroll
                    for (int i=0;i<8;++i)
                        acc[r][i] = fmaf(w0, m[r+ky][i],
                                    fmaf(w1, m[r+ky][i+1],
                                    fmaf(w2, m[r+ky][i+2], acc[r][i])));
            }
        }
        #pragma unroll
        for (int r=0;r<2;++r){
            ushort8 ov;
            #pragma unroll
            for (int i=0;i<8;++i){
                unsigned short uu = f2u(acc[r][i]);
                ov[i] = uu;
                int px = r*128 + px0 + i;
                *(unsigned short*)((char*)xs + px*128 + ((oc*2) ^ ((px&7)<<4))) = uu;
            }
            *reinterpret_cast<ushort8*>(x1out + ((size_t)b*DCC + oc)*HWS
                                        + (size_t)(y0+r)*WW + px0) = ov;
        }
    }
    __syncthreads();

    const unsigned short* pbuf = (const unsigned short*)plfrag;
    unsigned short* trw = &tr[wv][0];
    const int lpx0 = wv*64;

    #pragma unroll 1
    for (int oc=0; oc<4; ++oc){
        bf16x8 A1[2][2];
        #pragma unroll
        for (int t2=0;t2<2;++t2)
            #pragma unroll
            for (int kh=0;kh<2;++kh)
                A1[t2][kh] = ldfrag(pbuf, (oc*2+t2)*2+kh, lane);
        #pragma unroll
        for (int lt=0;lt<4;++lt){
            int px = lpx0 + lt*16 + col;
            bf16x8 B0 = *(const bf16x8*)((char*)xs + px*128 + ((g*16) ^ ((px&7)<<4)));
            bf16x8 B1 = *(const bf16x8*)((char*)xs + px*128 + ((64 + g*16) ^ ((px&7)<<4)));
            f32x4 D0 = *(const f32x4*)(l1b + oc*32 + g*4);
            f32x4 D1 = *(const f32x4*)(l1b + oc*32 + 16 + g*4);
            __builtin_amdgcn_s_setprio(1);
            D0 = __builtin_amdgcn_mfma_f32_16x16x32_bf16(A1[0][0], B0, D0, 0,0,0);
            D0 = __builtin_amdgcn_mfma_f32_16x16x32_bf16(A1[0][1], B1, D0, 0,0,0);
            D1 = __builtin_amdgcn_mfma_f32_16x16x32_bf16(A1[1][0], B0, D1, 0,0,0);
            D1 = __builtin_amdgcn_mfma_f32_16x16x32_bf16(A1[1][1], B1, D1, 0,0,0);
            __builtin_amdgcn_s_setprio(0);
            int lp = lt*16 + col;
            #pragma unroll
            for (int rr=0;rr<4;++rr){
                trw[(g*4+rr)*66 + lp]    = f2u(fgelu(D0[rr]));
                trw[(16+g*4+rr)*66 + lp] = f2u(fgelu(D1[rr]));
            }
        }
        {
            int ch2 = lane >> 1;
            int half = lane & 1;
            const unsigned short* srcp = trw + ch2*66 + half*32;
            bf16* dst = h1out + ((size_t)(b*HIDN + oc*32 + ch2))*HWS + sp0 + lpx0 + half*32;
            #pragma unroll
            for (int i=0;i<4;++i){
                ushort8 u8 = *reinterpret_cast<const ushort8*>(srcp + i*8);
                *reinterpret_cast<ushort8*>(dst + i*8) = u8;
            }
        }
    }
}

// ---------------------------------------------------------------- dwA: dwconv(h1)+gelu + lazy-h2 + gate + lin2 fused
__global__ __launch_bounds__(256) void k_dwA(
    const bf16* __restrict__ x1, const bf16* __restrict__ v,
    const bf16* __restrict__ h1, const bf16* __restrict__ wfrag,
    const float* __restrict__ l1b,
    const float* __restrict__ dww, const float* __restrict__ dwb,
    const float* __restrict__ l2b,
    bf16* __restrict__ xout,
    const float* __restrict__ xinit,   // non-null on last layer
    bf16* __restrict__ xsum)
{
    __shared__ __align__(16) unsigned short xs[128*64];    // 16 KB (center row)
    __shared__ __align__(16) unsigned short ubuf[2*8320];  // 33.3 KB
    const int t = threadIdx.x;
    const int lane = t & 63;
    const int wv = t >> 6;
    const int col = lane & 15;
    const int g = lane >> 4;
    const int blk0 = blockIdx.x;          // 2048 blocks
    const int blk = (blk0 & 7)*256 + (blk0 >> 3);   // XCD-contiguous rows
    const int b = blk >> 7;
    const int y = blk & 127;

    const int cj  = (t>>3) & 31;     // dw channel within chunk
    const int pxo = (t & 7) << 4;    // dw 16-px group

    const unsigned short* buf1 = (const unsigned short*)wfrag;
    const unsigned short* buf2 = buf1 + 8192;

    ushort8 pfa[3], pfb[3];
    unsigned short pfl[3], pfr[3];
    float pw9[9], pbj;
    auto LOADCHUNK = [&](int cc){
        int chg = cc*32 + cj;
        const bf16* h1p = h1 + ((size_t)(b*HIDN + chg))*HWS;
        #pragma unroll
        for (int ky=0; ky<3; ++ky){
            int gy = y + ky - 1;
            if (gy >= 0 && gy < HH){
                const bf16* rp = h1p + (size_t)gy*WW + pxo;
                pfa[ky] = *reinterpret_cast<const ushort8*>(rp);
                pfb[ky] = *reinterpret_cast<const ushort8*>(rp+8);
                pfl[ky] = (pxo>0)     ? *reinterpret_cast<const unsigned short*>(rp-1)  : 0;
                pfr[ky] = (pxo+16<WW) ? *reinterpret_cast<const unsigned short*>(rp+16) : 0;
            } else {
                #pragma unroll
                for (int i=0;i<8;++i){ pfa[ky][i]=0; pfb[ky][i]=0; }
                pfl[ky]=0; pfr[ky]=0;
            }
        }
        #pragma unroll
        for (int i=0;i<9;++i) pw9[i] = dww[chg*9+i];
        pbj = dwb[chg];
    };

    LOADCHUNK(0);

    {   // stage x-cat center row: 64ch x 128px
        const int ch = t & 63;
        const int wg = t >> 6;
        const bf16* src = (ch < DCC) ? x1 + ((size_t)b*DCC + ch)*HWS
                                     : v  + ((size_t)b*CC  + ch)*HWS;
        #pragma unroll
        for (int i=0;i<2;++i){
            int bufpx = (wg*2 + i) << 3;
            ushort8 val = *reinterpret_cast<const ushort8*>(src + (size_t)y*WW + bufpx);
            #pragma unroll
            for (int j=0;j<8;++j){
                int px = bufpx + j;
                *(unsigned short*)((char*)xs + px*128 + ((ch*2) ^ ((px&7)<<4))) = val[j];
            }
        }
    }
    __syncthreads();

    f32x4 Dx[2][4];
    #pragma unroll
    for (int q=0;q<2;++q)
        #pragma unroll
        for (int ot=0;ot<4;++ot)
            Dx[q][ot] = *(const f32x4*)(l2b + ot*16 + g*4);

    #pragma unroll 1
    for (int cc=0; cc<4; ++cc){
        unsigned short* ub = ubuf + (cc&1)*8320;
        ushort8 o0v, o1v;
        {
            float acc[16];
            #pragma unroll
            for (int i=0;i<16;++i) acc[i]=0.f;
            #pragma unroll
            for (int ky=0; ky<3; ++ky){
                float m[16];
                #pragma unroll
                for (int i=0;i<8;++i){ m[i]=u2f(pfa[ky][i]); m[8+i]=u2f(pfb[ky][i]); }
                float lf = u2f(pfl[ky]);
                float rt = u2f(pfr[ky]);
                float w0=pw9[ky*3], w1=pw9[ky*3+1], wv2=pw9[ky*3+2];
                #pragma unroll
                for (int i=0;i<16;++i){
                    float l  = i ? m[i-1] : lf;
                    float r_ = (i==15) ? rt : m[i+1];
                    acc[i] = fmaf(w0,l, fmaf(w1,m[i], fmaf(wv2,r_,acc[i])));
                }
            }
            #pragma unroll
            for (int i=0;i<8;++i){
                o0v[i] = f2u(fgelu(acc[i]+pbj));
                o1v[i] = f2u(fgelu(acc[8+i]+pbj));
            }
        }
        if (cc < 3) LOADCHUNK(cc+1);
        *(ushort8*)(ub + cj*260 + pxo)     = o0v;
        *(ushort8*)(ub + cj*260 + pxo + 8) = o1v;
        __syncthreads();
        {
            bf16x8 A1g[2][2];
            #pragma unroll
            for (int t2=0;t2<2;++t2)
                #pragma unroll
                for (int kh=0;kh<2;++kh)
                    A1g[t2][kh] = ldfrag(buf1, (cc*2+t2)*2+kh, lane);
            bf16x8 A2[4];
            #pragma unroll
            for (int ot=0;ot<4;++ot)
                A2[ot] = ldfrag(buf2, cc*4+ot, lane);
            #pragma unroll
            for (int q=0;q<2;++q){
                int px = (wv*2+q)*16 + col;
                bf16x8 B0 = *(const bf16x8*)((char*)xs + px*128 + ((g*16) ^ ((px&7)<<4)));
                bf16x8 B1 = *(const bf16x8*)((char*)xs + px*128 + ((64 + g*16) ^ ((px&7)<<4)));
                f32x4 D0 = *(const f32x4*)(l1b + 128 + cc*32 + g*4);
                f32x4 D1 = *(const f32x4*)(l1b + 128 + cc*32 + 16 + g*4);
                __builtin_amdgcn_s_setprio(1);
                D0 = __builtin_amdgcn_mfma_f32_16x16x32_bf16(A1g[0][0], B0, D0, 0,0,0);
                D0 = __builtin_amdgcn_mfma_f32_16x16x32_bf16(A1g[0][1], B1, D0, 0,0,0);
                D1 = __builtin_amdgcn_mfma_f32_16x16x32_bf16(A1g[1][0], B0, D1, 0,0,0);
                D1 = __builtin_amdgcn_mfma_f32_16x16x32_bf16(A1g[1][1], B1, D1, 0,0,0);
                __builtin_amdgcn_s_setprio(0);
                bf16x8 Bg;
                #pragma unroll
                for (int j=0;j<4;++j){
                    float u0 = u2f(ub[(g*4+j)*260 + px]);
                    float u1 = u2f(ub[(16+g*4+j)*260 + px]);
                    Bg[j]   = (short)f2u(u0 * fgelu(D0[j]));
                    Bg[4+j] = (short)f2u(u1 * fgelu(D1[j]));
                }
                __builtin_amdgcn_s_setprio(1);
                #pragma unroll
                for (int ot=0;ot<4;++ot)
                    Dx[q][ot] = __builtin_amdgcn_mfma_f32_16x16x32_bf16(A2[ot], Bg, Dx[q][ot], 0,0,0);
                __builtin_amdgcn_s_setprio(0);
            }
        }
    }
    __syncthreads();
    #pragma unroll
    for (int q=0;q<2;++q)
        #pragma unroll
        for (int ot=0;ot<4;++ot)
            #pragma unroll
            for (int rr=0;rr<4;++rr)
                ubuf[(ot*16 + g*4 + rr)*136 + (wv*2+q)*16 + col] = f2u(Dx[q][ot][rr]);
    __syncthreads();
    {
        int ch  = t >> 2;
        int pxb = (t & 3) * 32;
        size_t off = ((size_t)(b*CC + ch))*HWS + (size_t)y*WW + pxb;
        #pragma unroll
        for (int i=0;i<4;++i){
            ushort8 dv = *reinterpret_cast<const ushort8*>(ubuf + ch*136 + pxb + i*8);
            ushort8 vv = *reinterpret_cast<const ushort8*>(v + off + i*8);
            ushort8 ov;
            float rv[8];
            #pragma unroll
            for (int j=0;j<8;++j){
                rv[j] = u2f(dv[j]) + u2f(vv[j]);
                ov[j] = f2u(rv[j]);
            }
            *reinterpret_cast<ushort8*>(xout + off + i*8) = ov;
            if (xinit){
                float4v x0 = *reinterpret_cast<const float4v*>(xinit + off + i*8);
                float4v x1v = *reinterpret_cast<const float4v*>(xinit + off + i*8 + 4);
                ushort8 sv;
                sv[0]=f2u(rv[0]+x0.x); sv[1]=f2u(rv[1]+x0.y);
                sv[2]=f2u(rv[2]+x0.z); sv[3]=f2u(rv[3]+x0.w);
                sv[4]=f2u(rv[4]+x1v.x); sv[5]=f2u(rv[5]+x1v.y);
                sv[6]=f2u(rv[6]+x1v.z); sv[7]=f2u(rv[7]+x1v.w);
                *reinterpret_cast<ushort8*>(xsum + off + i*8) = sv;
            }
        }
    }
}

// ---------------------------------------------------------------- final conv (64->1, 3x3), 4 px/thread
__global__ __launch_bounds__(256) void k_final(
    const bf16* __restrict__ s, const float* __restrict__ w,
    const float* __restrict__ bias, float* __restrict__ out)
{
    int gid = blockIdx.x*256 + threadIdx.x;
    int b = gid >> 12;
    int sp4 = (gid & 4095) << 2;
    int y = sp4 >> 7, x0 = sp4 & 127;
    const bf16* sb = s + (size_t)b*CC*HWS;
    float acc[4];
    #pragma unroll
    for (int i=0;i<4;++i) acc[i] = bias[0];

    #pragma unroll 1
    for (int c=0;c<CC;++c){
        const bf16* ip = sb + (size_t)c*HWS;
        const float* wp = w + (size_t)c*9;
        #pragma unroll
        for (int ky=0;ky<3;++ky){
            int yy = y + ky - 1;
            float xv[6];
            if (yy >= 0 && yy < HH){
                const bf16* rp = ip + yy*WW + x0;
                ushort4v mv = *reinterpret_cast<const ushort4v*>(rp);
                xv[1]=u2f(mv[0]); xv[2]=u2f(mv[1]); xv[3]=u2f(mv[2]); xv[4]=u2f(mv[3]);
                xv[0] = (x0>0)    ? b2f(rp[-1]) : 0.f;
                xv[5] = (x0+4<WW) ? b2f(rp[4])  : 0.f;
            } else {
                #pragma unroll
                for (int i=0;i<6;++i) xv[i] = 0.f;
            }
            float w0 = wp[ky*3+0], w1 = wp[ky*3+1], w2 = wp[ky*3+2];
            #pragma unroll
            for (int i=0;i<4;++i)
                acc[i] = fmaf(w0, xv[i],
                         fmaf(w1, xv[i+1],
                         fmaf(w2, xv[i+2], acc[i])));
        }
    }
    float4v ov; ov.x=acc[0]; ov.y=acc[1]; ov.z=acc[2]; ov.w=acc[3];
    *reinterpret_cast<float4v*>(out + (size_t)gid*4) = ov;
}

// ---------------------------------------------------------------- launch
extern "C" void kernel_launch(void* const* d_in, const int* in_sizes, int n_in,
                              void* d_out, int out_size, void* d_ws, size_t ws_size,
                              hipStream_t stream)
{
    const float* x    = (const float*)d_in[0];
    const float* wz1  = (const float*)d_in[1];
    const float* bz1  = (const float*)d_in[2];
    const float* wz2  = (const float*)d_in[3];
    const float* bz2  = (const float*)d_in[4];
    const float* wf1  = (const float*)d_in[5];
    const float* bf1  = (const float*)d_in[6];
    const float* wf2  = (const float*)d_in[7];
    const float* bf2  = (const float*)d_in[8];
    const float* pw   = (const float*)d_in[9];
    const float* l1w  = (const float*)d_in[10];
    const float* l1b  = (const float*)d_in[11];
    const float* dww  = (const float*)d_in[12];
    const float* dwb  = (const float*)d_in[13];
    const float* l2w  = (const float*)d_in[14];
    const float* l2b  = (const float*)d_in[15];
    const float* ow   = (const float*)d_in[16];
    const float* obb  = (const float*)d_in[17];

    char* ws = (char*)d_ws;
    bf16* xc    = (bf16*)(ws);                    // 33,554,432 B
    bf16* v     = (bf16*)(ws + 33554432);         // 33,554,432 B
    bf16* x1    = (bf16*)(ws + 67108864);         //  8,388,608 B
    bf16* xsumb = (bf16*)(ws + 75497472);         // 33,554,432 B
    bf16* h1buf = (bf16*)(ws + 109051904);        // 67,108,864 B
    bf16* wfrag = (bf16*)(ws + 176160768);        // 3 x 80 KB

    k_wprep<<<3, 256, 0, stream>>>(l1w, l2w, wz1, wf1, wz2, wf2, wfrag);
    for (int l=0;l<3;++l){
        const bf16* wf = wfrag + (size_t)l*WFRAG_STRIDE;
        if (l == 0)
            k_gate<1><<<512, 256, 0, stream>>>(x, nullptr, wf + 24576,
                bz1 + l*CC, bz2 + l*CC, bf1 + l*CC, bf2 + l*CC, v);
        else
            k_gate<0><<<512, 256, 0, stream>>>(nullptr, xc, wf + 24576,
                bz1 + l*CC, bz2 + l*CC, bf1 + l*CC, bf2 + l*CC, v);
        k_pl1  <<<NPIX/256, 256, 0, stream>>>(v, pw + l*DCC*DCC*9,
                wf + 16384, l1b + l*256, x1, h1buf);
        k_dwA  <<<BB*HH, 256, 0, stream>>>(x1, v, h1buf, wf,
                l1b + l*256,
                dww + l*HIDN*9, dwb + l*HIDN,
                l2b + l*CC,
                xc, (l==2) ? x : nullptr, xsumb);
    }
    k_final<<<NPIX/(256*4), 256, 0, stream>>>(xsumb, ow, obb, (float*)d_out);
}